// Round 7
// baseline (354.105 us; speedup 1.0000x reference)
//
#include <hip/hip_runtime.h>
#include <math.h>

#define N_NODES 50000
#define N_EDGES 800000
#define DIM 64
#define HID 128
#define LAYERS 3
#define NGRAPH 128

#define SCAN_TILE 1024
#define SCAN_NB ((N_NODES + SCAN_TILE - 1) / SCAN_TILE)   // 49

#define POOL_ROWS 256
#define POOL_NB ((N_NODES + POOL_ROWS - 1) / POOL_ROWS)   // 196

typedef __attribute__((ext_vector_type(8))) short short8v;   // 8 bf16 (4 VGPR)
typedef __attribute__((ext_vector_type(4))) float f32x4;

__device__ __forceinline__ float bf2f(unsigned short u) {
    return __uint_as_float(((unsigned)u) << 16);
}
__device__ __forceinline__ unsigned short f2bf(float x) {
    unsigned u = __float_as_uint(x);
    unsigned r = (u + 0x7fff + ((u >> 16) & 1)) >> 16;   // RNE
    return (unsigned short)r;
}

// ---------------------------------------------------------------------------
// CSR build: histogram of dst
// ---------------------------------------------------------------------------
__global__ void count_kernel(const int* __restrict__ dst, int* __restrict__ counts) {
    int e = blockIdx.x * blockDim.x + threadIdx.x;
    if (e >= N_EDGES) return;
    atomicAdd(&counts[dst[e]], 1);
}

__global__ void scan_partial_kernel(const int* __restrict__ counts,
                                    int* __restrict__ bsum) {
    __shared__ int red[256];
    const int b = blockIdx.x, tid = threadIdx.x;
    const int base = b * SCAN_TILE + tid * 4;
    int s = 0;
    if (base + 3 < N_NODES) {
        int4 v = *reinterpret_cast<const int4*>(counts + base);
        s = v.x + v.y + v.z + v.w;
    } else {
        for (int i = 0; i < 4; ++i)
            if (base + i < N_NODES) s += counts[base + i];
    }
    red[tid] = s;
    __syncthreads();
    for (int off = 128; off > 0; off >>= 1) {
        if (tid < off) red[tid] += red[tid + off];
        __syncthreads();
    }
    if (tid == 0) bsum[b] = red[0];
}

__global__ void scan_mid_kernel(const int* __restrict__ bsum,
                                int* __restrict__ bpre,
                                int* __restrict__ offsets) {
    int tid = threadIdx.x;   // 64 threads, one wave
    int orig = (tid < SCAN_NB) ? bsum[tid] : 0;
    int v = orig;
    for (int off = 1; off < 64; off <<= 1) {
        int u = __shfl_up(v, off);
        if (tid >= off) v += u;
    }
    if (tid < SCAN_NB) bpre[tid] = v - orig;
    if (tid == 0) offsets[N_NODES] = N_EDGES;
}

__global__ void scan_final_kernel(const int* __restrict__ counts,
                                  const int* __restrict__ bpre,
                                  int* __restrict__ offsets,
                                  int* __restrict__ cursor) {
    __shared__ int pre[256];
    const int b = blockIdx.x, tid = threadIdx.x;
    const int base = b * SCAN_TILE + tid * 4;
    int c[4];
    int s = 0;
#pragma unroll
    for (int i = 0; i < 4; ++i) {
        c[i] = (base + i < N_NODES) ? counts[base + i] : 0;
        s += c[i];
    }
    pre[tid] = s;
    __syncthreads();
    for (int off = 1; off < 256; off <<= 1) {
        int v = (tid >= off) ? pre[tid - off] : 0;
        __syncthreads();
        pre[tid] += v;
        __syncthreads();
    }
    int run = bpre[b] + pre[tid] - s;
#pragma unroll
    for (int i = 0; i < 4; ++i) {
        if (base + i < N_NODES) {
            offsets[base + i] = run;
            cursor[base + i]  = run;
            run += c[i];
        }
    }
}

__global__ void place_kernel(const int* __restrict__ src,
                             const int* __restrict__ dst,
                             int* __restrict__ cursor,
                             int* __restrict__ csr_src) {
    int e = blockIdx.x * blockDim.x + threadIdx.x;
    if (e >= N_EDGES) return;
    int pos = atomicAdd(&cursor[dst[e]], 1);
    csr_src[pos] = src[e];
}

// ---------------------------------------------------------------------------
// weight repack: W[L][K][C] f32 -> frag-major bf16 P[L][KT][CT][64 lanes][8]
// lane l (li=l&15, hi=l>>4) gets W[kt*32 + hi*8 + j][ct*16 + li], j=0..7
// ---------------------------------------------------------------------------
template<int K, int C>
__global__ void repack_kernel(const float* __restrict__ W, unsigned short* __restrict__ P) {
    constexpr int KT = K / 32, CT = C / 16;
    int t = blockIdx.x * 256 + threadIdx.x;
    if (t >= LAYERS * KT * CT * 64) return;
    int lane = t & 63; int rest = t >> 6;
    int ct = rest % CT; rest /= CT;
    int kt = rest % KT; int l = rest / KT;
    int li = lane & 15, hi = lane >> 4;
    const float* Wl = W + (size_t)l * K * C;
    short8v o;
#pragma unroll
    for (int j = 0; j < 8; ++j)
        o[j] = (short)f2bf(Wl[(size_t)(kt * 32 + hi * 8 + j) * C + ct * 16 + li]);
    *reinterpret_cast<short8v*>(P + ((size_t)l * KT * CT * 64 + (size_t)(kt * CT + ct) * 64 + lane) * 8) = o;
}

// ---------------------------------------------------------------------------
// fused layer: gather (in-register A-frags) -> MFMA W1 -> tanh -> LDS xpose
//              -> MFMA W2 -> tanh -> LDS xpose -> MFMA W3 -> tanh(tanh) -> out
// one wave (64 thr) per 16 rows. IN and OUT are DISTINCT buffers (ping-pong):
// neighbor reads hit arbitrary rows of the input, so in-place would race
// against other blocks of the same dispatch (round-6 bug).
// A/B frag convention (same as repack): k = kt*32 + hi*8 + j, row/col = li.
// D convention (m89): col = li, row = hi*4 + j.
// LDS tile: row-major [16][128] bf16, swizzle byte ^= (row&7)<<4 (G4/T2).
// ---------------------------------------------------------------------------
template<bool F32IN>
__global__ __launch_bounds__(64) void layer_fused_kernel(
        const float* __restrict__ xf, const unsigned short* __restrict__ xb,
        const int* __restrict__ offsets, const int* __restrict__ csr_src,
        const unsigned short* __restrict__ pw1, const float* __restrict__ bias1,
        const unsigned short* __restrict__ pw2, const float* __restrict__ bias2,
        const unsigned short* __restrict__ pw3, const float* __restrict__ bias3,
        unsigned short* __restrict__ outx) {
    __shared__ unsigned short tileA[16 * 128];
    __shared__ unsigned short tileB[16 * 128];
    const int lane = threadIdx.x;
    const int li = lane & 15, hi = lane >> 4;
    const int r = blockIdx.x * 16 + li;          // 3125*16 == N exactly, no tail

    // ---- gather: ag[k'] = x[r][k] + sum_nbr x[s][k], k = kt*32 + hi*8 + j
    float ag[16];
    {
        if (F32IN) {
            const float* xr = xf + (size_t)r * DIM;
#pragma unroll
            for (int kt = 0; kt < 2; ++kt) {
                float4 a = *reinterpret_cast<const float4*>(xr + kt * 32 + hi * 8);
                float4 b = *reinterpret_cast<const float4*>(xr + kt * 32 + hi * 8 + 4);
                ag[kt*8+0] = a.x; ag[kt*8+1] = a.y; ag[kt*8+2] = a.z; ag[kt*8+3] = a.w;
                ag[kt*8+4] = b.x; ag[kt*8+5] = b.y; ag[kt*8+6] = b.z; ag[kt*8+7] = b.w;
            }
        } else {
            const unsigned short* xr = xb + (size_t)r * DIM;
            short8v v0 = *reinterpret_cast<const short8v*>(xr + hi * 8);
            short8v v1 = *reinterpret_cast<const short8v*>(xr + 32 + hi * 8);
#pragma unroll
            for (int j = 0; j < 8; ++j) {
                ag[j]     = bf2f((unsigned short)v0[j]);
                ag[8 + j] = bf2f((unsigned short)v1[j]);
            }
        }
    }
    int p = offsets[r], pe = offsets[r + 1];
    for (; p < pe; ++p) {
        int s = csr_src[p];
        if (F32IN) {
            const float* xs = xf + (size_t)s * DIM;
#pragma unroll
            for (int kt = 0; kt < 2; ++kt) {
                float4 a = *reinterpret_cast<const float4*>(xs + kt * 32 + hi * 8);
                float4 b = *reinterpret_cast<const float4*>(xs + kt * 32 + hi * 8 + 4);
                ag[kt*8+0] += a.x; ag[kt*8+1] += a.y; ag[kt*8+2] += a.z; ag[kt*8+3] += a.w;
                ag[kt*8+4] += b.x; ag[kt*8+5] += b.y; ag[kt*8+6] += b.z; ag[kt*8+7] += b.w;
            }
        } else {
            const unsigned short* xs = xb + (size_t)s * DIM;
            short8v v0 = *reinterpret_cast<const short8v*>(xs + hi * 8);
            short8v v1 = *reinterpret_cast<const short8v*>(xs + 32 + hi * 8);
#pragma unroll
            for (int j = 0; j < 8; ++j) {
                ag[j]     += bf2f((unsigned short)v0[j]);
                ag[8 + j] += bf2f((unsigned short)v1[j]);
            }
        }
    }
    short8v af[2];
#pragma unroll
    for (int kt = 0; kt < 2; ++kt)
#pragma unroll
        for (int j = 0; j < 8; ++j) af[kt][j] = (short)f2bf(ag[kt * 8 + j]);

    // ---- gemm1: K=64 (KT=2), C=128 (CT=8) ----
    f32x4 acc1[8];
#pragma unroll
    for (int ct = 0; ct < 8; ++ct) acc1[ct] = (f32x4){0.f, 0.f, 0.f, 0.f};
#pragma unroll
    for (int ct = 0; ct < 8; ++ct)
#pragma unroll
        for (int kt = 0; kt < 2; ++kt) {
            short8v bfr = *reinterpret_cast<const short8v*>(pw1 + ((size_t)(kt * 8 + ct) * 64 + lane) * 8);
            acc1[ct] = __builtin_amdgcn_mfma_f32_16x16x32_bf16(af[kt], bfr, acc1[ct], 0, 0, 0);
        }
    // bias+tanh, transpose D->A via tileA (swizzled)
#pragma unroll
    for (int ct = 0; ct < 8; ++ct) {
        float bv = bias1[ct * 16 + li];
#pragma unroll
        for (int j = 0; j < 4; ++j) {
            int row = hi * 4 + j;
            unsigned off = (unsigned)(row * 256 + (ct * 16 + li) * 2) ^ ((unsigned)(row & 7) << 4);
            *reinterpret_cast<unsigned short*>(reinterpret_cast<char*>(tileA) + off) =
                f2bf(tanhf(acc1[ct][j] + bv));
        }
    }
    __syncthreads();   // 1 wave: cheap; guarantees LDS write->read ordering
    short8v af2[4];
#pragma unroll
    for (int kt = 0; kt < 4; ++kt) {
        unsigned off = (unsigned)(li * 256 + (kt * 32 + hi * 8) * 2) ^ ((unsigned)(li & 7) << 4);
        af2[kt] = *reinterpret_cast<const short8v*>(reinterpret_cast<const char*>(tileA) + off);
    }

    // ---- gemm2: K=128 (KT=4), C=128 (CT=8) ----
    f32x4 acc2[8];
#pragma unroll
    for (int ct = 0; ct < 8; ++ct) acc2[ct] = (f32x4){0.f, 0.f, 0.f, 0.f};
#pragma unroll
    for (int ct = 0; ct < 8; ++ct)
#pragma unroll
        for (int kt = 0; kt < 4; ++kt) {
            short8v bfr = *reinterpret_cast<const short8v*>(pw2 + ((size_t)(kt * 8 + ct) * 64 + lane) * 8);
            acc2[ct] = __builtin_amdgcn_mfma_f32_16x16x32_bf16(af2[kt], bfr, acc2[ct], 0, 0, 0);
        }
#pragma unroll
    for (int ct = 0; ct < 8; ++ct) {
        float bv = bias2[ct * 16 + li];
#pragma unroll
        for (int j = 0; j < 4; ++j) {
            int row = hi * 4 + j;
            unsigned off = (unsigned)(row * 256 + (ct * 16 + li) * 2) ^ ((unsigned)(row & 7) << 4);
            *reinterpret_cast<unsigned short*>(reinterpret_cast<char*>(tileB) + off) =
                f2bf(tanhf(acc2[ct][j] + bv));
        }
    }
    __syncthreads();
    short8v af3[4];
#pragma unroll
    for (int kt = 0; kt < 4; ++kt) {
        unsigned off = (unsigned)(li * 256 + (kt * 32 + hi * 8) * 2) ^ ((unsigned)(li & 7) << 4);
        af3[kt] = *reinterpret_cast<const short8v*>(reinterpret_cast<const char*>(tileB) + off);
    }

    // ---- gemm3: K=128 (KT=4), C=64 (CT=4) ----
    f32x4 acc3[4];
#pragma unroll
    for (int ct = 0; ct < 4; ++ct) acc3[ct] = (f32x4){0.f, 0.f, 0.f, 0.f};
#pragma unroll
    for (int ct = 0; ct < 4; ++ct)
#pragma unroll
        for (int kt = 0; kt < 4; ++kt) {
            short8v bfr = *reinterpret_cast<const short8v*>(pw3 + ((size_t)(kt * 4 + ct) * 64 + lane) * 8);
            acc3[ct] = __builtin_amdgcn_mfma_f32_16x16x32_bf16(af3[kt], bfr, acc3[ct], 0, 0, 0);
        }
    // epilogue: tanh(tanh(.)) and store row-major bf16
#pragma unroll
    for (int ct = 0; ct < 4; ++ct) {
        float bv = bias3[ct * 16 + li];
#pragma unroll
        for (int j = 0; j < 4; ++j) {
            int row = blockIdx.x * 16 + hi * 4 + j;
            float v = tanhf(tanhf(acc3[ct][j] + bv));
            outx[(size_t)row * DIM + ct * 16 + li] = f2bf(v);
        }
    }
}

// ---------------------------------------------------------------------------
// mean pool (node-parallel, bf16 input) + finalize
// ---------------------------------------------------------------------------
__global__ void pool_partial_kernel(const unsigned short* __restrict__ x,
                                    const int* __restrict__ batch,
                                    float* __restrict__ sums) {
    const int tid = threadIdx.x;
    const int d = tid & 63;
    const int rg = tid >> 6;
    int row = blockIdx.x * POOL_ROWS + rg;
    const int rowend = min(N_NODES, (blockIdx.x + 1) * POOL_ROWS);
    float acc = 0.f;
    int cur = -1;
    for (; row < rowend; row += 4) {
        int g = batch[row];
        if (g != cur) {
            if (cur >= 0) atomicAdd(&sums[cur * DIM + d], acc);
            acc = 0.f;
            cur = g;
        }
        acc += bf2f(x[(size_t)row * DIM + d]);
    }
    if (cur >= 0) atomicAdd(&sums[cur * DIM + d], acc);
}

__global__ void pool_final_kernel(const float* __restrict__ sums,
                                  const int* __restrict__ batch,
                                  float* __restrict__ out) {
    const int g = blockIdx.x;
    const int d = threadIdx.x;
    int lo = 0, hi = N_NODES;
    while (lo < hi) { int m = (lo + hi) >> 1; if (batch[m] < g) lo = m + 1; else hi = m; }
    int start = lo;
    hi = N_NODES;
    while (lo < hi) { int m = (lo + hi) >> 1; if (batch[m] < g + 1) lo = m + 1; else hi = m; }
    float cnt = (float)(lo - start);
    out[g * DIM + d] = sums[g * DIM + d] / fmaxf(cnt, 1.f);
}

// ---------------------------------------------------------------------------
extern "C" void kernel_launch(void* const* d_in, const int* in_sizes, int n_in,
                              void* d_out, int out_size, void* d_ws, size_t ws_size,
                              hipStream_t stream) {
    const float* attrs = (const float*)d_in[0];
    const float* W1    = (const float*)d_in[1];
    const float* b1    = (const float*)d_in[2];
    const float* W2    = (const float*)d_in[3];
    const float* b2    = (const float*)d_in[4];
    const float* W3    = (const float*)d_in[5];
    const float* b3    = (const float*)d_in[6];
    const int* edge_index = (const int*)d_in[7];
    const int* batch      = (const int*)d_in[8];
    float* out = (float*)d_out;

    unsigned short* buf0 = (unsigned short*)d_ws;               // N*64 bf16
    unsigned short* buf1 = buf0 + (size_t)N_NODES * DIM;        // N*64 bf16
    unsigned short* pW1  = buf1 + (size_t)N_NODES * DIM;        // 24576
    unsigned short* pW2  = pW1 + 24576;                         // 49152
    unsigned short* pW3  = pW2 + 49152;                         // 24576
    float* psums  = (float*)(pW3 + 24576);                      // G*64 f32
    int* offsets  = (int*)(psums + NGRAPH * DIM);               // N+1
    int* csr_src  = offsets + N_NODES + 1;                      // E
    int* counts   = csr_src + N_EDGES;                          // N
    int* cursor   = counts + N_NODES;                           // N
    int* bsum     = cursor + N_NODES;                           // SCAN_NB
    int* bpre     = bsum + SCAN_NB;                             // SCAN_NB

    const int* src = edge_index;
    const int* dst = edge_index + N_EDGES;

    const int edge_blocks  = (N_EDGES + 255) / 256;
    const int layer_blocks = N_NODES / 16;                      // 3125, exact

    // ---- CSR build (once; edge list is layer-invariant) ----
    hipMemsetAsync(counts, 0, (size_t)N_NODES * sizeof(int), stream);
    count_kernel<<<edge_blocks, 256, 0, stream>>>(dst, counts);
    scan_partial_kernel<<<SCAN_NB, 256, 0, stream>>>(counts, bsum);
    scan_mid_kernel<<<1, 64, 0, stream>>>(bsum, bpre, offsets);
    scan_final_kernel<<<SCAN_NB, 256, 0, stream>>>(counts, bpre, offsets, cursor);
    place_kernel<<<edge_blocks, 256, 0, stream>>>(src, dst, cursor, csr_src);

    // ---- weight repack to frag-major bf16 (once) ----
    repack_kernel<DIM, HID><<<(LAYERS * 2 * 8 * 64 + 255) / 256, 256, 0, stream>>>(W1, pW1);
    repack_kernel<HID, HID><<<(LAYERS * 4 * 8 * 64 + 255) / 256, 256, 0, stream>>>(W2, pW2);
    repack_kernel<HID, DIM><<<(LAYERS * 4 * 4 * 64 + 255) / 256, 256, 0, stream>>>(W3, pW3);

    // ---- fused layers, ping-pong activations: attrs -> buf0 -> buf1 -> buf0
    for (int l = 0; l < LAYERS; ++l) {
        const unsigned short* w1 = pW1 + (size_t)l * 2 * 8 * 64 * 8;
        const unsigned short* w2 = pW2 + (size_t)l * 4 * 8 * 64 * 8;
        const unsigned short* w3 = pW3 + (size_t)l * 4 * 4 * 64 * 8;
        const float* bb1 = b1 + (size_t)l * HID;
        const float* bb2 = b2 + (size_t)l * HID;
        const float* bb3 = b3 + (size_t)l * DIM;
        if (l == 0)
            layer_fused_kernel<true><<<layer_blocks, 64, 0, stream>>>(
                attrs, nullptr, offsets, csr_src, w1, bb1, w2, bb2, w3, bb3, buf0);
        else {
            const unsigned short* in = (l == 1) ? buf0 : buf1;
            unsigned short* outb     = (l == 1) ? buf1 : buf0;
            layer_fused_kernel<false><<<layer_blocks, 64, 0, stream>>>(
                nullptr, in, offsets, csr_src, w1, bb1, w2, bb2, w3, bb3, outb);
        }
    }

    // ---- mean pool (reads buf0 after layer 2) ----
    hipMemsetAsync(psums, 0, (size_t)NGRAPH * DIM * sizeof(float), stream);
    pool_partial_kernel<<<POOL_NB, 256, 0, stream>>>(buf0, batch, psums);
    pool_final_kernel<<<NGRAPH, DIM, 0, stream>>>(psums, batch, out);
}

// Round 8
// 343.131 us; speedup vs baseline: 1.0320x; 1.0320x over previous
//
#include <hip/hip_runtime.h>
#include <math.h>

#define N_NODES 50000
#define N_EDGES 800000
#define DIM 64
#define HID 128
#define LAYERS 3
#define NGRAPH 128

#define SCAN_TILE 1024
#define SCAN_NB ((N_NODES + SCAN_TILE - 1) / SCAN_TILE)   // 49

#define POOL_ROWS 256
#define POOL_NB ((N_NODES + POOL_ROWS - 1) / POOL_ROWS)   // 196

typedef __attribute__((ext_vector_type(8))) short short8v;   // 8 bf16 (4 VGPR)
typedef __attribute__((ext_vector_type(4))) float f32x4;

__device__ __forceinline__ float bf2f(unsigned short u) {
    return __uint_as_float(((unsigned)u) << 16);
}
__device__ __forceinline__ unsigned short f2bf(float x) {
    unsigned u = __float_as_uint(x);
    unsigned r = (u + 0x7fff + ((u >> 16) & 1)) >> 16;   // RNE
    return (unsigned short)r;
}

// ---------------------------------------------------------------------------
// CSR build: histogram of dst
// ---------------------------------------------------------------------------
__global__ void count_kernel(const int* __restrict__ dst, int* __restrict__ counts) {
    int e = blockIdx.x * blockDim.x + threadIdx.x;
    if (e >= N_EDGES) return;
    atomicAdd(&counts[dst[e]], 1);
}

__global__ void scan_partial_kernel(const int* __restrict__ counts,
                                    int* __restrict__ bsum) {
    __shared__ int red[256];
    const int b = blockIdx.x, tid = threadIdx.x;
    const int base = b * SCAN_TILE + tid * 4;
    int s = 0;
    if (base + 3 < N_NODES) {
        int4 v = *reinterpret_cast<const int4*>(counts + base);
        s = v.x + v.y + v.z + v.w;
    } else {
        for (int i = 0; i < 4; ++i)
            if (base + i < N_NODES) s += counts[base + i];
    }
    red[tid] = s;
    __syncthreads();
    for (int off = 128; off > 0; off >>= 1) {
        if (tid < off) red[tid] += red[tid + off];
        __syncthreads();
    }
    if (tid == 0) bsum[b] = red[0];
}

__global__ void scan_mid_kernel(const int* __restrict__ bsum,
                                int* __restrict__ bpre,
                                int* __restrict__ offsets) {
    int tid = threadIdx.x;   // 64 threads, one wave
    int orig = (tid < SCAN_NB) ? bsum[tid] : 0;
    int v = orig;
    for (int off = 1; off < 64; off <<= 1) {
        int u = __shfl_up(v, off);
        if (tid >= off) v += u;
    }
    if (tid < SCAN_NB) bpre[tid] = v - orig;
    if (tid == 0) offsets[N_NODES] = N_EDGES;
}

__global__ void scan_final_kernel(const int* __restrict__ counts,
                                  const int* __restrict__ bpre,
                                  int* __restrict__ offsets,
                                  int* __restrict__ cursor) {
    __shared__ int pre[256];
    const int b = blockIdx.x, tid = threadIdx.x;
    const int base = b * SCAN_TILE + tid * 4;
    int c[4];
    int s = 0;
#pragma unroll
    for (int i = 0; i < 4; ++i) {
        c[i] = (base + i < N_NODES) ? counts[base + i] : 0;
        s += c[i];
    }
    pre[tid] = s;
    __syncthreads();
    for (int off = 1; off < 256; off <<= 1) {
        int v = (tid >= off) ? pre[tid - off] : 0;
        __syncthreads();
        pre[tid] += v;
        __syncthreads();
    }
    int run = bpre[b] + pre[tid] - s;
#pragma unroll
    for (int i = 0; i < 4; ++i) {
        if (base + i < N_NODES) {
            offsets[base + i] = run;
            cursor[base + i]  = run;
            run += c[i];
        }
    }
}

__global__ void place_kernel(const int* __restrict__ src,
                             const int* __restrict__ dst,
                             int* __restrict__ cursor,
                             int* __restrict__ csr_src) {
    int e = blockIdx.x * blockDim.x + threadIdx.x;
    if (e >= N_EDGES) return;
    int pos = atomicAdd(&cursor[dst[e]], 1);
    csr_src[pos] = src[e];
}

// ---------------------------------------------------------------------------
// weight repack: W[L][K][C] f32 -> frag-major bf16 P[L][KT][CT][64 lanes][8]
// lane l (li=l&15, hi=l>>4) gets W[kt*32 + hi*8 + j][ct*16 + li], j=0..7
// ---------------------------------------------------------------------------
template<int K, int C>
__global__ void repack_kernel(const float* __restrict__ W, unsigned short* __restrict__ P) {
    constexpr int KT = K / 32, CT = C / 16;
    int t = blockIdx.x * 256 + threadIdx.x;
    if (t >= LAYERS * KT * CT * 64) return;
    int lane = t & 63; int rest = t >> 6;
    int ct = rest % CT; rest /= CT;
    int kt = rest % KT; int l = rest / KT;
    int li = lane & 15, hi = lane >> 4;
    const float* Wl = W + (size_t)l * K * C;
    short8v o;
#pragma unroll
    for (int j = 0; j < 8; ++j)
        o[j] = (short)f2bf(Wl[(size_t)(kt * 32 + hi * 8 + j) * C + ct * 16 + li]);
    *reinterpret_cast<short8v*>(P + ((size_t)l * KT * CT * 64 + (size_t)(kt * CT + ct) * 64 + lane) * 8) = o;
}

// ---------------------------------------------------------------------------
// gather: aggx[i] = bf16( x[i] + sum over incoming edges of x[src] )
// 8 lanes per node, 8 channels per lane; f32 accumulate. High-occupancy,
// separate dispatch (round-7 lesson: fusing this serial walk into the MLP
// starves the whole layer of waves).
// ---------------------------------------------------------------------------
template<bool F32IN>
__global__ void gather_kernel(const float* __restrict__ xf,
                              const unsigned short* __restrict__ xb,
                              const int* __restrict__ offsets,
                              const int* __restrict__ csr_src,
                              unsigned short* __restrict__ aggx) {
    int idx = blockIdx.x * blockDim.x + threadIdx.x;
    int node = idx >> 3;
    int ch0 = (idx & 7) * 8;
    if (node >= N_NODES) return;
    float acc[8];
    if (F32IN) {
        const float4* p = reinterpret_cast<const float4*>(xf + (size_t)node * DIM + ch0);
        float4 a = p[0], b = p[1];
        acc[0] = a.x; acc[1] = a.y; acc[2] = a.z; acc[3] = a.w;
        acc[4] = b.x; acc[5] = b.y; acc[6] = b.z; acc[7] = b.w;
    } else {
        short8v v = *reinterpret_cast<const short8v*>(xb + (size_t)node * DIM + ch0);
#pragma unroll
        for (int j = 0; j < 8; ++j) acc[j] = bf2f((unsigned short)v[j]);
    }
    int p = offsets[node], end = offsets[node + 1];
    for (; p < end; ++p) {
        int s = csr_src[p];
        if (F32IN) {
            const float4* q = reinterpret_cast<const float4*>(xf + (size_t)s * DIM + ch0);
            float4 a = q[0], b = q[1];
            acc[0] += a.x; acc[1] += a.y; acc[2] += a.z; acc[3] += a.w;
            acc[4] += b.x; acc[5] += b.y; acc[6] += b.z; acc[7] += b.w;
        } else {
            short8v v = *reinterpret_cast<const short8v*>(xb + (size_t)s * DIM + ch0);
#pragma unroll
            for (int j = 0; j < 8; ++j) acc[j] += bf2f((unsigned short)v[j]);
        }
    }
    short8v o;
#pragma unroll
    for (int j = 0; j < 8; ++j) o[j] = (short)f2bf(acc[j]);
    *reinterpret_cast<short8v*>(aggx + (size_t)node * DIM + ch0) = o;
}

// ---------------------------------------------------------------------------
// fused MLP: out = tanh(tanh(tanh(tanh(A@W1+b1)@W2+b2)@W3+b3))
// Row-local (no neighbor reads) -> streaming, race-free, in-place-safe.
// 256 thr / 4 waves; wave owns 16 rows end-to-end. A-frags from global,
// D->A transposes via per-wave LDS tile (reused), swizzle byte^=(row&7)<<4.
// A/B frag convention (matches repack): k = kt*32 + hi*8 + j, row/col = li.
// D convention (m89): col = li, row = hi*4 + j.
// ---------------------------------------------------------------------------
__global__ __launch_bounds__(256) void mlp_fused_kernel(
        const unsigned short* __restrict__ A,
        const unsigned short* __restrict__ pw1, const float* __restrict__ bias1,
        const unsigned short* __restrict__ pw2, const float* __restrict__ bias2,
        const unsigned short* __restrict__ pw3, const float* __restrict__ bias3,
        unsigned short* __restrict__ outx) {
    __shared__ unsigned short tile[4][16 * 128];   // per-wave 4 KB, reused twice
    const int tid = threadIdx.x;
    const int wave = tid >> 6, lane = tid & 63;
    const int li = lane & 15, hi = lane >> 4;
    const int r0 = blockIdx.x * 64 + wave * 16;

    int ar = r0 + li;
    if (ar >= N_NODES) ar = N_NODES - 1;           // clamped read; store guarded
    char* tw = reinterpret_cast<char*>(tile[wave]);

    // ---- A-frags (K=64, KT=2) ----
    short8v af[2];
#pragma unroll
    for (int kt = 0; kt < 2; ++kt)
        af[kt] = *reinterpret_cast<const short8v*>(A + (size_t)ar * DIM + kt * 32 + hi * 8);

    // ---- gemm1: K=64, C=128 ----
    f32x4 acc1[8];
#pragma unroll
    for (int ct = 0; ct < 8; ++ct) acc1[ct] = (f32x4){0.f, 0.f, 0.f, 0.f};
#pragma unroll
    for (int ct = 0; ct < 8; ++ct)
#pragma unroll
        for (int kt = 0; kt < 2; ++kt) {
            short8v bfr = *reinterpret_cast<const short8v*>(pw1 + ((size_t)(kt * 8 + ct) * 64 + lane) * 8);
            acc1[ct] = __builtin_amdgcn_mfma_f32_16x16x32_bf16(af[kt], bfr, acc1[ct], 0, 0, 0);
        }
#pragma unroll
    for (int ct = 0; ct < 8; ++ct) {
        float bv = bias1[ct * 16 + li];
#pragma unroll
        for (int j = 0; j < 4; ++j) {
            int row = hi * 4 + j;
            unsigned off = (unsigned)(row * 256 + (ct * 16 + li) * 2) ^ ((unsigned)(row & 7) << 4);
            *reinterpret_cast<unsigned short*>(tw + off) = f2bf(tanhf(acc1[ct][j] + bv));
        }
    }
    __syncthreads();
    short8v af2[4];
#pragma unroll
    for (int kt = 0; kt < 4; ++kt) {
        unsigned off = (unsigned)(li * 256 + (kt * 32 + hi * 8) * 2) ^ ((unsigned)(li & 7) << 4);
        af2[kt] = *reinterpret_cast<const short8v*>(tw + off);
    }
    __syncthreads();

    // ---- gemm2: K=128, C=128 ----
    f32x4 acc2[8];
#pragma unroll
    for (int ct = 0; ct < 8; ++ct) acc2[ct] = (f32x4){0.f, 0.f, 0.f, 0.f};
#pragma unroll
    for (int ct = 0; ct < 8; ++ct)
#pragma unroll
        for (int kt = 0; kt < 4; ++kt) {
            short8v bfr = *reinterpret_cast<const short8v*>(pw2 + ((size_t)(kt * 8 + ct) * 64 + lane) * 8);
            acc2[ct] = __builtin_amdgcn_mfma_f32_16x16x32_bf16(af2[kt], bfr, acc2[ct], 0, 0, 0);
        }
#pragma unroll
    for (int ct = 0; ct < 8; ++ct) {
        float bv = bias2[ct * 16 + li];
#pragma unroll
        for (int j = 0; j < 4; ++j) {
            int row = hi * 4 + j;
            unsigned off = (unsigned)(row * 256 + (ct * 16 + li) * 2) ^ ((unsigned)(row & 7) << 4);
            *reinterpret_cast<unsigned short*>(tw + off) = f2bf(tanhf(acc2[ct][j] + bv));
        }
    }
    __syncthreads();
    short8v af3[4];
#pragma unroll
    for (int kt = 0; kt < 4; ++kt) {
        unsigned off = (unsigned)(li * 256 + (kt * 32 + hi * 8) * 2) ^ ((unsigned)(li & 7) << 4);
        af3[kt] = *reinterpret_cast<const short8v*>(tw + off);
    }

    // ---- gemm3: K=128, C=64 ----
    f32x4 acc3[4];
#pragma unroll
    for (int ct = 0; ct < 4; ++ct) acc3[ct] = (f32x4){0.f, 0.f, 0.f, 0.f};
#pragma unroll
    for (int ct = 0; ct < 4; ++ct)
#pragma unroll
        for (int kt = 0; kt < 4; ++kt) {
            short8v bfr = *reinterpret_cast<const short8v*>(pw3 + ((size_t)(kt * 4 + ct) * 64 + lane) * 8);
            acc3[ct] = __builtin_amdgcn_mfma_f32_16x16x32_bf16(af3[kt], bfr, acc3[ct], 0, 0, 0);
        }
#pragma unroll
    for (int ct = 0; ct < 4; ++ct) {
        float bv = bias3[ct * 16 + li];
#pragma unroll
        for (int j = 0; j < 4; ++j) {
            int row = r0 + hi * 4 + j;
            if (row >= N_NODES) continue;
            float v = tanhf(tanhf(acc3[ct][j] + bv));
            outx[(size_t)row * DIM + ct * 16 + li] = f2bf(v);
        }
    }
}

// ---------------------------------------------------------------------------
// mean pool (node-parallel, bf16 input) + finalize
// ---------------------------------------------------------------------------
__global__ void pool_partial_kernel(const unsigned short* __restrict__ x,
                                    const int* __restrict__ batch,
                                    float* __restrict__ sums) {
    const int tid = threadIdx.x;
    const int d = tid & 63;
    const int rg = tid >> 6;
    int row = blockIdx.x * POOL_ROWS + rg;
    const int rowend = min(N_NODES, (blockIdx.x + 1) * POOL_ROWS);
    float acc = 0.f;
    int cur = -1;
    for (; row < rowend; row += 4) {
        int g = batch[row];
        if (g != cur) {
            if (cur >= 0) atomicAdd(&sums[cur * DIM + d], acc);
            acc = 0.f;
            cur = g;
        }
        acc += bf2f(x[(size_t)row * DIM + d]);
    }
    if (cur >= 0) atomicAdd(&sums[cur * DIM + d], acc);
}

__global__ void pool_final_kernel(const float* __restrict__ sums,
                                  const int* __restrict__ batch,
                                  float* __restrict__ out) {
    const int g = blockIdx.x;
    const int d = threadIdx.x;
    int lo = 0, hi = N_NODES;
    while (lo < hi) { int m = (lo + hi) >> 1; if (batch[m] < g) lo = m + 1; else hi = m; }
    int start = lo;
    hi = N_NODES;
    while (lo < hi) { int m = (lo + hi) >> 1; if (batch[m] < g + 1) lo = m + 1; else hi = m; }
    float cnt = (float)(lo - start);
    out[g * DIM + d] = sums[g * DIM + d] / fmaxf(cnt, 1.f);
}

// ---------------------------------------------------------------------------
extern "C" void kernel_launch(void* const* d_in, const int* in_sizes, int n_in,
                              void* d_out, int out_size, void* d_ws, size_t ws_size,
                              hipStream_t stream) {
    const float* attrs = (const float*)d_in[0];
    const float* W1    = (const float*)d_in[1];
    const float* b1    = (const float*)d_in[2];
    const float* W2    = (const float*)d_in[3];
    const float* b2    = (const float*)d_in[4];
    const float* W3    = (const float*)d_in[5];
    const float* b3    = (const float*)d_in[6];
    const int* edge_index = (const int*)d_in[7];
    const int* batch      = (const int*)d_in[8];
    float* out = (float*)d_out;

    unsigned short* xbuf = (unsigned short*)d_ws;               // N*64 bf16
    unsigned short* aggx = xbuf + (size_t)N_NODES * DIM;        // N*64 bf16
    unsigned short* pW1  = aggx + (size_t)N_NODES * DIM;        // 24576
    unsigned short* pW2  = pW1 + 24576;                         // 49152
    unsigned short* pW3  = pW2 + 49152;                         // 24576
    float* psums  = (float*)(pW3 + 24576);                      // G*64 f32
    int* offsets  = (int*)(psums + NGRAPH * DIM);               // N+1
    int* csr_src  = offsets + N_NODES + 1;                      // E
    int* counts   = csr_src + N_EDGES;                          // N
    int* cursor   = counts + N_NODES;                           // N
    int* bsum     = cursor + N_NODES;                           // SCAN_NB
    int* bpre     = bsum + SCAN_NB;                             // SCAN_NB

    const int* src = edge_index;
    const int* dst = edge_index + N_EDGES;

    const int edge_blocks   = (N_EDGES + 255) / 256;
    const int gather_blocks = (N_NODES * 8 + 255) / 256;
    const int mlp_blocks    = (N_NODES + 63) / 64;              // 782

    // ---- CSR build (once; edge list is layer-invariant) ----
    hipMemsetAsync(counts, 0, (size_t)N_NODES * sizeof(int), stream);
    count_kernel<<<edge_blocks, 256, 0, stream>>>(dst, counts);
    scan_partial_kernel<<<SCAN_NB, 256, 0, stream>>>(counts, bsum);
    scan_mid_kernel<<<1, 64, 0, stream>>>(bsum, bpre, offsets);
    scan_final_kernel<<<SCAN_NB, 256, 0, stream>>>(counts, bpre, offsets, cursor);
    place_kernel<<<edge_blocks, 256, 0, stream>>>(src, dst, cursor, csr_src);

    // ---- weight repack to frag-major bf16 (once) ----
    repack_kernel<DIM, HID><<<(LAYERS * 2 * 8 * 64 + 255) / 256, 256, 0, stream>>>(W1, pW1);
    repack_kernel<HID, HID><<<(LAYERS * 4 * 8 * 64 + 255) / 256, 256, 0, stream>>>(W2, pW2);
    repack_kernel<HID, DIM><<<(LAYERS * 4 * 4 * 64 + 255) / 256, 256, 0, stream>>>(W3, pW3);

    // ---- layers: gather (separate, high-occupancy) + fused row-local MLP ----
    for (int l = 0; l < LAYERS; ++l) {
        if (l == 0)
            gather_kernel<true><<<gather_blocks, 256, 0, stream>>>(attrs, nullptr, offsets, csr_src, aggx);
        else
            gather_kernel<false><<<gather_blocks, 256, 0, stream>>>(nullptr, xbuf, offsets, csr_src, aggx);
        mlp_fused_kernel<<<mlp_blocks, 256, 0, stream>>>(
            aggx,
            pW1 + (size_t)l * 2 * 8 * 64 * 8, b1 + (size_t)l * HID,
            pW2 + (size_t)l * 4 * 8 * 64 * 8, b2 + (size_t)l * HID,
            pW3 + (size_t)l * 4 * 4 * 64 * 8, b3 + (size_t)l * DIM,
            xbuf);
    }

    // ---- mean pool ----
    hipMemsetAsync(psums, 0, (size_t)NGRAPH * DIM * sizeof(float), stream);
    pool_partial_kernel<<<POOL_NB, 256, 0, stream>>>(xbuf, batch, psums);
    pool_final_kernel<<<NGRAPH, DIM, 0, stream>>>(psums, batch, out);
}

// Round 9
// 273.880 us; speedup vs baseline: 1.2929x; 1.2529x over previous
//
#include <hip/hip_runtime.h>
#include <math.h>

#define N_NODES 50000
#define N_EDGES 800000
#define DIM 64
#define HID 128
#define LAYERS 3
#define NGRAPH 128

#define SCAN_TILE 1024
#define SCAN_NB ((N_NODES + SCAN_TILE - 1) / SCAN_TILE)   // 49

#define POOL_ROWS 256
#define POOL_NB ((N_NODES + POOL_ROWS - 1) / POOL_ROWS)   // 196

typedef __attribute__((ext_vector_type(8))) short short8v;   // 8 bf16 (4 VGPR)
typedef __attribute__((ext_vector_type(4))) float f32x4;

__device__ __forceinline__ float bf2f(unsigned short u) {
    return __uint_as_float(((unsigned)u) << 16);
}
__device__ __forceinline__ unsigned short f2bf(float x) {
    unsigned u = __float_as_uint(x);
    unsigned r = (u + 0x7fff + ((u >> 16) & 1)) >> 16;   // RNE
    return (unsigned short)r;
}
// fast tanh: 1 - 2/(1+e^{2x}), clamp |x|<=9 (tanh(9) == 1 to 8 digits).
// ~7 VALU ops vs ~30 for libm tanhf; error ~1e-6 << bf16 rounding.
__device__ __forceinline__ float fast_tanh(float x) {
    float xc = fminf(fmaxf(x, -9.0f), 9.0f);
    float y = __expf(2.0f * xc);
    return 1.0f - 2.0f * __builtin_amdgcn_rcpf(y + 1.0f);
}

// ---------------------------------------------------------------------------
// CSR build: histogram of dst
// ---------------------------------------------------------------------------
__global__ void count_kernel(const int* __restrict__ dst, int* __restrict__ counts) {
    int e = blockIdx.x * blockDim.x + threadIdx.x;
    if (e >= N_EDGES) return;
    atomicAdd(&counts[dst[e]], 1);
}

__global__ void scan_partial_kernel(const int* __restrict__ counts,
                                    int* __restrict__ bsum) {
    __shared__ int red[256];
    const int b = blockIdx.x, tid = threadIdx.x;
    const int base = b * SCAN_TILE + tid * 4;
    int s = 0;
    if (base + 3 < N_NODES) {
        int4 v = *reinterpret_cast<const int4*>(counts + base);
        s = v.x + v.y + v.z + v.w;
    } else {
        for (int i = 0; i < 4; ++i)
            if (base + i < N_NODES) s += counts[base + i];
    }
    red[tid] = s;
    __syncthreads();
    for (int off = 128; off > 0; off >>= 1) {
        if (tid < off) red[tid] += red[tid + off];
        __syncthreads();
    }
    if (tid == 0) bsum[b] = red[0];
}

__global__ void scan_mid_kernel(const int* __restrict__ bsum,
                                int* __restrict__ bpre,
                                int* __restrict__ offsets) {
    int tid = threadIdx.x;   // 64 threads, one wave
    int orig = (tid < SCAN_NB) ? bsum[tid] : 0;
    int v = orig;
    for (int off = 1; off < 64; off <<= 1) {
        int u = __shfl_up(v, off);
        if (tid >= off) v += u;
    }
    if (tid < SCAN_NB) bpre[tid] = v - orig;
    if (tid == 0) offsets[N_NODES] = N_EDGES;
}

__global__ void scan_final_kernel(const int* __restrict__ counts,
                                  const int* __restrict__ bpre,
                                  int* __restrict__ offsets,
                                  int* __restrict__ cursor) {
    __shared__ int pre[256];
    const int b = blockIdx.x, tid = threadIdx.x;
    const int base = b * SCAN_TILE + tid * 4;
    int c[4];
    int s = 0;
#pragma unroll
    for (int i = 0; i < 4; ++i) {
        c[i] = (base + i < N_NODES) ? counts[base + i] : 0;
        s += c[i];
    }
    pre[tid] = s;
    __syncthreads();
    for (int off = 1; off < 256; off <<= 1) {
        int v = (tid >= off) ? pre[tid - off] : 0;
        __syncthreads();
        pre[tid] += v;
        __syncthreads();
    }
    int run = bpre[b] + pre[tid] - s;
#pragma unroll
    for (int i = 0; i < 4; ++i) {
        if (base + i < N_NODES) {
            offsets[base + i] = run;
            cursor[base + i]  = run;
            run += c[i];
        }
    }
}

__global__ void place_kernel(const int* __restrict__ src,
                             const int* __restrict__ dst,
                             int* __restrict__ cursor,
                             int* __restrict__ csr_src) {
    int e = blockIdx.x * blockDim.x + threadIdx.x;
    if (e >= N_EDGES) return;
    int pos = atomicAdd(&cursor[dst[e]], 1);
    csr_src[pos] = src[e];
}

// ---------------------------------------------------------------------------
// weight repack: W[L][K][C] f32 -> frag-major bf16 P[L][KT][CT][64 lanes][8]
// lane l (li=l&15, hi=l>>4) gets W[kt*32 + hi*8 + j][ct*16 + li], j=0..7
// ---------------------------------------------------------------------------
template<int K, int C>
__global__ void repack_kernel(const float* __restrict__ W, unsigned short* __restrict__ P) {
    constexpr int KT = K / 32, CT = C / 16;
    int t = blockIdx.x * 256 + threadIdx.x;
    if (t >= LAYERS * KT * CT * 64) return;
    int lane = t & 63; int rest = t >> 6;
    int ct = rest % CT; rest /= CT;
    int kt = rest % KT; int l = rest / KT;
    int li = lane & 15, hi = lane >> 4;
    const float* Wl = W + (size_t)l * K * C;
    short8v o;
#pragma unroll
    for (int j = 0; j < 8; ++j)
        o[j] = (short)f2bf(Wl[(size_t)(kt * 32 + hi * 8 + j) * C + ct * 16 + li]);
    *reinterpret_cast<short8v*>(P + ((size_t)l * KT * CT * 64 + (size_t)(kt * CT + ct) * 64 + lane) * 8) = o;
}

// ---------------------------------------------------------------------------
// gather: aggx[i] = bf16( x[i] + sum over incoming edges of x[src] )
// 8 lanes per node, 8 channels per lane; f32 accumulate (separate dispatch:
// round-7 lesson — fusing the serial walk into the MLP starves it of waves).
// ---------------------------------------------------------------------------
template<bool F32IN>
__global__ void gather_kernel(const float* __restrict__ xf,
                              const unsigned short* __restrict__ xb,
                              const int* __restrict__ offsets,
                              const int* __restrict__ csr_src,
                              unsigned short* __restrict__ aggx) {
    int idx = blockIdx.x * blockDim.x + threadIdx.x;
    int node = idx >> 3;
    int ch0 = (idx & 7) * 8;
    if (node >= N_NODES) return;
    float acc[8];
    if (F32IN) {
        const float4* p = reinterpret_cast<const float4*>(xf + (size_t)node * DIM + ch0);
        float4 a = p[0], b = p[1];
        acc[0] = a.x; acc[1] = a.y; acc[2] = a.z; acc[3] = a.w;
        acc[4] = b.x; acc[5] = b.y; acc[6] = b.z; acc[7] = b.w;
    } else {
        short8v v = *reinterpret_cast<const short8v*>(xb + (size_t)node * DIM + ch0);
#pragma unroll
        for (int j = 0; j < 8; ++j) acc[j] = bf2f((unsigned short)v[j]);
    }
    int p = offsets[node], end = offsets[node + 1];
    for (; p < end; ++p) {
        int s = csr_src[p];
        if (F32IN) {
            const float4* q = reinterpret_cast<const float4*>(xf + (size_t)s * DIM + ch0);
            float4 a = q[0], b = q[1];
            acc[0] += a.x; acc[1] += a.y; acc[2] += a.z; acc[3] += a.w;
            acc[4] += b.x; acc[5] += b.y; acc[6] += b.z; acc[7] += b.w;
        } else {
            short8v v = *reinterpret_cast<const short8v*>(xb + (size_t)s * DIM + ch0);
#pragma unroll
            for (int j = 0; j < 8; ++j) acc[j] += bf2f((unsigned short)v[j]);
        }
    }
    short8v o;
#pragma unroll
    for (int j = 0; j < 8; ++j) o[j] = (short)f2bf(acc[j]);
    *reinterpret_cast<short8v*>(aggx + (size_t)node * DIM + ch0) = o;
}

// ---------------------------------------------------------------------------
// fused MLP, 4-way C-split (round-8 lesson: wave-per-16-rows-owning-all-C is
// grid-starved at 3 waves/SIMD; splitting C across 4 waves gives 12.5k waves).
// block = 16 rows, 4 waves. gemm1/gemm2: wave w owns cols [32w,32w+32)
// (ct = 2w, 2w+1); gemm3: ct = w. Inter-gemm transposes via block LDS tiles
// (tileA -> tileB, 2 barriers; B-writes never alias A-reads).
// A/B frag convention (matches repack): k = kt*32 + hi*8 + j, row/col = li.
// D convention (m89): col = li, row = hi*4 + j.
// LDS tiles [16][128] bf16, swizzle byte ^= (row&7)<<4 (G4/T2).
// ---------------------------------------------------------------------------
__global__ __launch_bounds__(256) void mlp_fused_kernel(
        const unsigned short* __restrict__ A,
        const unsigned short* __restrict__ pw1, const float* __restrict__ bias1,
        const unsigned short* __restrict__ pw2, const float* __restrict__ bias2,
        const unsigned short* __restrict__ pw3, const float* __restrict__ bias3,
        unsigned short* __restrict__ outx) {
    __shared__ unsigned short tileA[16 * 128];
    __shared__ unsigned short tileB[16 * 128];
    const int tid = threadIdx.x;
    const int wave = tid >> 6, lane = tid & 63;
    const int li = lane & 15, hi = lane >> 4;
    const int r0 = blockIdx.x * 16;              // 3125*16 == N exactly, no tail
    char* tA = reinterpret_cast<char*>(tileA);
    char* tB = reinterpret_cast<char*>(tileB);

    // ---- A-frags (K=64, KT=2); all 4 waves load the same 16 rows (L1 hit)
    short8v af[2];
#pragma unroll
    for (int kt = 0; kt < 2; ++kt)
        af[kt] = *reinterpret_cast<const short8v*>(A + (size_t)(r0 + li) * DIM + kt * 32 + hi * 8);

    // ---- gemm1: K=64, C=128; this wave: ct = 2*wave + c, c in {0,1}
    f32x4 acc1[2];
#pragma unroll
    for (int c = 0; c < 2; ++c) acc1[c] = (f32x4){0.f, 0.f, 0.f, 0.f};
#pragma unroll
    for (int c = 0; c < 2; ++c) {
        const int ct = 2 * wave + c;
#pragma unroll
        for (int kt = 0; kt < 2; ++kt) {
            short8v bfr = *reinterpret_cast<const short8v*>(pw1 + ((size_t)(kt * 8 + ct) * 64 + lane) * 8);
            acc1[c] = __builtin_amdgcn_mfma_f32_16x16x32_bf16(af[kt], bfr, acc1[c], 0, 0, 0);
        }
    }
#pragma unroll
    for (int c = 0; c < 2; ++c) {
        const int ct = 2 * wave + c;
        float bv = bias1[ct * 16 + li];
#pragma unroll
        for (int j = 0; j < 4; ++j) {
            int row = hi * 4 + j;
            unsigned off = (unsigned)(row * 256 + (ct * 16 + li) * 2) ^ ((unsigned)(row & 7) << 4);
            *reinterpret_cast<unsigned short*>(tA + off) = f2bf(fast_tanh(acc1[c][j] + bv));
        }
    }
    __syncthreads();

    // ---- gemm2: K=128, C=128; A-frags (full K) from tileA
    short8v af2[4];
#pragma unroll
    for (int kt = 0; kt < 4; ++kt) {
        unsigned off = (unsigned)(li * 256 + (kt * 32 + hi * 8) * 2) ^ ((unsigned)(li & 7) << 4);
        af2[kt] = *reinterpret_cast<const short8v*>(tA + off);
    }
    f32x4 acc2[2];
#pragma unroll
    for (int c = 0; c < 2; ++c) acc2[c] = (f32x4){0.f, 0.f, 0.f, 0.f};
#pragma unroll
    for (int c = 0; c < 2; ++c) {
        const int ct = 2 * wave + c;
#pragma unroll
        for (int kt = 0; kt < 4; ++kt) {
            short8v bfr = *reinterpret_cast<const short8v*>(pw2 + ((size_t)(kt * 8 + ct) * 64 + lane) * 8);
            acc2[c] = __builtin_amdgcn_mfma_f32_16x16x32_bf16(af2[kt], bfr, acc2[c], 0, 0, 0);
        }
    }
#pragma unroll
    for (int c = 0; c < 2; ++c) {
        const int ct = 2 * wave + c;
        float bv = bias2[ct * 16 + li];
#pragma unroll
        for (int j = 0; j < 4; ++j) {
            int row = hi * 4 + j;
            unsigned off = (unsigned)(row * 256 + (ct * 16 + li) * 2) ^ ((unsigned)(row & 7) << 4);
            *reinterpret_cast<unsigned short*>(tB + off) = f2bf(fast_tanh(acc2[c][j] + bv));
        }
    }
    __syncthreads();

    // ---- gemm3: K=128, C=64; this wave: ct = wave
    short8v af3[4];
#pragma unroll
    for (int kt = 0; kt < 4; ++kt) {
        unsigned off = (unsigned)(li * 256 + (kt * 32 + hi * 8) * 2) ^ ((unsigned)(li & 7) << 4);
        af3[kt] = *reinterpret_cast<const short8v*>(tB + off);
    }
    f32x4 acc3 = (f32x4){0.f, 0.f, 0.f, 0.f};
#pragma unroll
    for (int kt = 0; kt < 4; ++kt) {
        short8v bfr = *reinterpret_cast<const short8v*>(pw3 + ((size_t)(kt * 4 + wave) * 64 + lane) * 8);
        acc3 = __builtin_amdgcn_mfma_f32_16x16x32_bf16(af3[kt], bfr, acc3, 0, 0, 0);
    }
    {
        float bv = bias3[wave * 16 + li];
#pragma unroll
        for (int j = 0; j < 4; ++j) {
            int row = r0 + hi * 4 + j;
            float v = fast_tanh(fast_tanh(acc3[j] + bv));
            outx[(size_t)row * DIM + wave * 16 + li] = f2bf(v);
        }
    }
}

// ---------------------------------------------------------------------------
// mean pool (node-parallel, bf16 input) + finalize
// ---------------------------------------------------------------------------
__global__ void pool_partial_kernel(const unsigned short* __restrict__ x,
                                    const int* __restrict__ batch,
                                    float* __restrict__ sums) {
    const int tid = threadIdx.x;
    const int d = tid & 63;
    const int rg = tid >> 6;
    int row = blockIdx.x * POOL_ROWS + rg;
    const int rowend = min(N_NODES, (blockIdx.x + 1) * POOL_ROWS);
    float acc = 0.f;
    int cur = -1;
    for (; row < rowend; row += 4) {
        int g = batch[row];
        if (g != cur) {
            if (cur >= 0) atomicAdd(&sums[cur * DIM + d], acc);
            acc = 0.f;
            cur = g;
        }
        acc += bf2f(x[(size_t)row * DIM + d]);
    }
    if (cur >= 0) atomicAdd(&sums[cur * DIM + d], acc);
}

__global__ void pool_final_kernel(const float* __restrict__ sums,
                                  const int* __restrict__ batch,
                                  float* __restrict__ out) {
    const int g = blockIdx.x;
    const int d = threadIdx.x;
    int lo = 0, hi = N_NODES;
    while (lo < hi) { int m = (lo + hi) >> 1; if (batch[m] < g) lo = m + 1; else hi = m; }
    int start = lo;
    hi = N_NODES;
    while (lo < hi) { int m = (lo + hi) >> 1; if (batch[m] < g + 1) lo = m + 1; else hi = m; }
    float cnt = (float)(lo - start);
    out[g * DIM + d] = sums[g * DIM + d] / fmaxf(cnt, 1.f);
}

// ---------------------------------------------------------------------------
extern "C" void kernel_launch(void* const* d_in, const int* in_sizes, int n_in,
                              void* d_out, int out_size, void* d_ws, size_t ws_size,
                              hipStream_t stream) {
    const float* attrs = (const float*)d_in[0];
    const float* W1    = (const float*)d_in[1];
    const float* b1    = (const float*)d_in[2];
    const float* W2    = (const float*)d_in[3];
    const float* b2    = (const float*)d_in[4];
    const float* W3    = (const float*)d_in[5];
    const float* b3    = (const float*)d_in[6];
    const int* edge_index = (const int*)d_in[7];
    const int* batch      = (const int*)d_in[8];
    float* out = (float*)d_out;

    unsigned short* xbuf = (unsigned short*)d_ws;               // N*64 bf16
    unsigned short* aggx = xbuf + (size_t)N_NODES * DIM;        // N*64 bf16
    unsigned short* pW1  = aggx + (size_t)N_NODES * DIM;        // 24576
    unsigned short* pW2  = pW1 + 24576;                         // 49152
    unsigned short* pW3  = pW2 + 49152;                         // 24576
    float* psums  = (float*)(pW3 + 24576);                      // G*64 f32
    int* offsets  = (int*)(psums + NGRAPH * DIM);               // N+1
    int* csr_src  = offsets + N_NODES + 1;                      // E
    int* counts   = csr_src + N_EDGES;                          // N
    int* cursor   = counts + N_NODES;                           // N
    int* bsum     = cursor + N_NODES;                           // SCAN_NB
    int* bpre     = bsum + SCAN_NB;                             // SCAN_NB

    const int* src = edge_index;
    const int* dst = edge_index + N_EDGES;

    const int edge_blocks   = (N_EDGES + 255) / 256;
    const int gather_blocks = (N_NODES * 8 + 255) / 256;
    const int mlp_blocks    = N_NODES / 16;                     // 3125, exact

    // ---- CSR build (once; edge list is layer-invariant) ----
    hipMemsetAsync(counts, 0, (size_t)N_NODES * sizeof(int), stream);
    count_kernel<<<edge_blocks, 256, 0, stream>>>(dst, counts);
    scan_partial_kernel<<<SCAN_NB, 256, 0, stream>>>(counts, bsum);
    scan_mid_kernel<<<1, 64, 0, stream>>>(bsum, bpre, offsets);
    scan_final_kernel<<<SCAN_NB, 256, 0, stream>>>(counts, bpre, offsets, cursor);
    place_kernel<<<edge_blocks, 256, 0, stream>>>(src, dst, cursor, csr_src);

    // ---- weight repack to frag-major bf16 (once) ----
    repack_kernel<DIM, HID><<<(LAYERS * 2 * 8 * 64 + 255) / 256, 256, 0, stream>>>(W1, pW1);
    repack_kernel<HID, HID><<<(LAYERS * 4 * 8 * 64 + 255) / 256, 256, 0, stream>>>(W2, pW2);
    repack_kernel<HID, DIM><<<(LAYERS * 4 * 4 * 64 + 255) / 256, 256, 0, stream>>>(W3, pW3);

    // ---- layers: gather (separate, high-occupancy) + fused row-local MLP ----
    for (int l = 0; l < LAYERS; ++l) {
        if (l == 0)
            gather_kernel<true><<<gather_blocks, 256, 0, stream>>>(attrs, nullptr, offsets, csr_src, aggx);
        else
            gather_kernel<false><<<gather_blocks, 256, 0, stream>>>(nullptr, xbuf, offsets, csr_src, aggx);
        mlp_fused_kernel<<<mlp_blocks, 256, 0, stream>>>(
            aggx,
            pW1 + (size_t)l * 2 * 8 * 64 * 8, b1 + (size_t)l * HID,
            pW2 + (size_t)l * 4 * 8 * 64 * 8, b2 + (size_t)l * HID,
            pW3 + (size_t)l * 4 * 4 * 64 * 8, b3 + (size_t)l * DIM,
            xbuf);
    }

    // ---- mean pool ----
    hipMemsetAsync(psums, 0, (size_t)NGRAPH * DIM * sizeof(float), stream);
    pool_partial_kernel<<<POOL_NB, 256, 0, stream>>>(xbuf, batch, psums);
    pool_final_kernel<<<NGRAPH, DIM, 0, stream>>>(psums, batch, out);
}

// Round 10
// 230.425 us; speedup vs baseline: 1.5367x; 1.1886x over previous
//
#include <hip/hip_runtime.h>
#include <math.h>

#define N_NODES 50000
#define N_EDGES 800000
#define DIM 64
#define HID 128
#define LAYERS 3
#define NGRAPH 128

#define SCAN_TILE 1024
#define SCAN_NB ((N_NODES + SCAN_TILE - 1) / SCAN_TILE)   // 49

#define POOL_ROWS 256
#define POOL_NB ((N_NODES + POOL_ROWS - 1) / POOL_ROWS)   // 196

typedef __attribute__((ext_vector_type(8))) short short8v;   // 8 bf16 (4 VGPR)
typedef __attribute__((ext_vector_type(4))) float f32x4;

__device__ __forceinline__ float bf2f(unsigned short u) {
    return __uint_as_float(((unsigned)u) << 16);
}
__device__ __forceinline__ unsigned short f2bf(float x) {
    unsigned u = __float_as_uint(x);
    unsigned r = (u + 0x7fff + ((u >> 16) & 1)) >> 16;   // RNE
    return (unsigned short)r;
}
// fast tanh: 1 - 2/(1+e^{2x}), clamp |x|<=9; err ~1e-6 << bf16 rounding
__device__ __forceinline__ float fast_tanh(float x) {
    float xc = fminf(fmaxf(x, -9.0f), 9.0f);
    float y = __expf(2.0f * xc);
    return 1.0f - 2.0f * __builtin_amdgcn_rcpf(y + 1.0f);
}

// ---------------------------------------------------------------------------
// CSR build. count also records each edge's rank (atomicAdd return) so
// place needs no atomic (round-9: place was top-1 with 800k atomic RMWs).
// ---------------------------------------------------------------------------
__global__ void count_kernel(const int* __restrict__ dst,
                             int* __restrict__ counts,
                             int* __restrict__ rank) {
    int e = blockIdx.x * blockDim.x + threadIdx.x;
    if (e >= N_EDGES) return;
    rank[e] = atomicAdd(&counts[dst[e]], 1);
}

__global__ void scan_partial_kernel(const int* __restrict__ counts,
                                    int* __restrict__ bsum) {
    __shared__ int red[256];
    const int b = blockIdx.x, tid = threadIdx.x;
    const int base = b * SCAN_TILE + tid * 4;
    int s = 0;
    if (base + 3 < N_NODES) {
        int4 v = *reinterpret_cast<const int4*>(counts + base);
        s = v.x + v.y + v.z + v.w;
    } else {
        for (int i = 0; i < 4; ++i)
            if (base + i < N_NODES) s += counts[base + i];
    }
    red[tid] = s;
    __syncthreads();
    for (int off = 128; off > 0; off >>= 1) {
        if (tid < off) red[tid] += red[tid + off];
        __syncthreads();
    }
    if (tid == 0) bsum[b] = red[0];
}

__global__ void scan_mid_kernel(const int* __restrict__ bsum,
                                int* __restrict__ bpre,
                                int* __restrict__ offsets) {
    int tid = threadIdx.x;   // 64 threads, one wave
    int orig = (tid < SCAN_NB) ? bsum[tid] : 0;
    int v = orig;
    for (int off = 1; off < 64; off <<= 1) {
        int u = __shfl_up(v, off);
        if (tid >= off) v += u;
    }
    if (tid < SCAN_NB) bpre[tid] = v - orig;
    if (tid == 0) offsets[N_NODES] = N_EDGES;
}

__global__ void scan_final_kernel(const int* __restrict__ counts,
                                  const int* __restrict__ bpre,
                                  int* __restrict__ offsets) {
    __shared__ int pre[256];
    const int b = blockIdx.x, tid = threadIdx.x;
    const int base = b * SCAN_TILE + tid * 4;
    int c[4];
    int s = 0;
#pragma unroll
    for (int i = 0; i < 4; ++i) {
        c[i] = (base + i < N_NODES) ? counts[base + i] : 0;
        s += c[i];
    }
    pre[tid] = s;
    __syncthreads();
    for (int off = 1; off < 256; off <<= 1) {
        int v = (tid >= off) ? pre[tid - off] : 0;
        __syncthreads();
        pre[tid] += v;
        __syncthreads();
    }
    int run = bpre[b] + pre[tid] - s;
#pragma unroll
    for (int i = 0; i < 4; ++i) {
        if (base + i < N_NODES) {
            offsets[base + i] = run;
            run += c[i];
        }
    }
}

__global__ void place_kernel(const int* __restrict__ src,
                             const int* __restrict__ dst,
                             const int* __restrict__ rank,
                             const int* __restrict__ offsets,
                             int* __restrict__ csr_src) {
    int e = blockIdx.x * blockDim.x + threadIdx.x;
    if (e >= N_EDGES) return;
    csr_src[offsets[dst[e]] + rank[e]] = src[e];
}

// ---------------------------------------------------------------------------
// weight repack: W[L][K][C] f32 -> frag-major bf16 P[L][KT][CT][64 lanes][8]
// lane l (li=l&15, hi=l>>4) gets W[kt*32 + hi*8 + j][ct*16 + li], j=0..7
// ---------------------------------------------------------------------------
template<int K, int C>
__global__ void repack_kernel(const float* __restrict__ W, unsigned short* __restrict__ P) {
    constexpr int KT = K / 32, CT = C / 16;
    int t = blockIdx.x * 256 + threadIdx.x;
    if (t >= LAYERS * KT * CT * 64) return;
    int lane = t & 63; int rest = t >> 6;
    int ct = rest % CT; rest /= CT;
    int kt = rest % KT; int l = rest / KT;
    int li = lane & 15, hi = lane >> 4;
    const float* Wl = W + (size_t)l * K * C;
    short8v o;
#pragma unroll
    for (int j = 0; j < 8; ++j)
        o[j] = (short)f2bf(Wl[(size_t)(kt * 32 + hi * 8 + j) * C + ct * 16 + li]);
    *reinterpret_cast<short8v*>(P + ((size_t)l * KT * CT * 64 + (size_t)(kt * CT + ct) * 64 + lane) * 8) = o;
}

// ---------------------------------------------------------------------------
// fused GIN layer: edge-walk gather (16 thr/node, f32 acc) -> agg LDS tile
// -> MFMA W1 -> tanh -> LDS xpose -> MFMA W2 -> tanh -> xpose -> MFMA W3
// -> tanh(tanh) -> out.  block = 16 rows, 4 waves C-split (round-9 structure;
// round-7's fusion failed at 4 thr/node + 1 wave/block).
// IN and OUT are DISTINCT buffers (ping-pong) - neighbor reads are random
// rows, in-place would race across blocks (round-6 bug).
// agg tile [16 rows][64 ch] bf16 (128 B row stride); tileA/B [16][128]
// (256 B stride); all swizzled byte ^= (row&7)<<4 (G4/T2).
// Frag convention (matches repack): k = kt*32 + hi*8 + j, row/col = li.
// D convention (m89): col = li, row = hi*4 + j.
// ---------------------------------------------------------------------------
template<bool F32IN>
__global__ __launch_bounds__(256) void gnn_layer_kernel(
        const float* __restrict__ xf, const unsigned short* __restrict__ xb,
        const int* __restrict__ offsets, const int* __restrict__ csr_src,
        const unsigned short* __restrict__ pw1, const float* __restrict__ bias1,
        const unsigned short* __restrict__ pw2, const float* __restrict__ bias2,
        const unsigned short* __restrict__ pw3, const float* __restrict__ bias3,
        unsigned short* __restrict__ outx) {
    __shared__ unsigned short agg[16 * 64];      // 2 KB
    __shared__ unsigned short tileA[16 * 128];   // 4 KB
    __shared__ unsigned short tileB[16 * 128];   // 4 KB
    const int tid = threadIdx.x;
    const int wave = tid >> 6, lane = tid & 63;
    const int li = lane & 15, hi = lane >> 4;
    const int r0 = blockIdx.x * 16;              // 3125*16 == N exactly
    char* tG = reinterpret_cast<char*>(agg);
    char* tA = reinterpret_cast<char*>(tileA);
    char* tB = reinterpret_cast<char*>(tileB);

    // ---- phase 1: gather. 16 threads per node, 4 channels each ----
    {
        const int nr = tid >> 4;                 // node row 0..15
        const int q  = tid & 15;                 // channel group (4 ch)
        const int n  = r0 + nr;
        float acc[4];
        if (F32IN) {
            float4 v = *reinterpret_cast<const float4*>(xf + (size_t)n * DIM + q * 4);
            acc[0] = v.x; acc[1] = v.y; acc[2] = v.z; acc[3] = v.w;
        } else {
            ushort4 v = *reinterpret_cast<const ushort4*>(xb + (size_t)n * DIM + q * 4);
            acc[0] = bf2f(v.x); acc[1] = bf2f(v.y); acc[2] = bf2f(v.z); acc[3] = bf2f(v.w);
        }
        int p = offsets[n], pe = offsets[n + 1];
        for (; p < pe; ++p) {
            int s = csr_src[p];                  // broadcast across the 16 lanes
            if (F32IN) {
                float4 v = *reinterpret_cast<const float4*>(xf + (size_t)s * DIM + q * 4);
                acc[0] += v.x; acc[1] += v.y; acc[2] += v.z; acc[3] += v.w;
            } else {
                ushort4 v = *reinterpret_cast<const ushort4*>(xb + (size_t)s * DIM + q * 4);
                acc[0] += bf2f(v.x); acc[1] += bf2f(v.y); acc[2] += bf2f(v.z); acc[3] += bf2f(v.w);
            }
        }
        ushort4 o;
        o.x = f2bf(acc[0]); o.y = f2bf(acc[1]); o.z = f2bf(acc[2]); o.w = f2bf(acc[3]);
        unsigned off = (unsigned)(nr * 128 + q * 8) ^ ((unsigned)(nr & 7) << 4);
        *reinterpret_cast<ushort4*>(tG + off) = o;
    }
    __syncthreads();

    // ---- A-frags from agg tile (row = li, k = kt*32 + hi*8 + j) ----
    short8v af[2];
#pragma unroll
    for (int kt = 0; kt < 2; ++kt) {
        unsigned off = (unsigned)(li * 128 + (kt * 32 + hi * 8) * 2) ^ ((unsigned)(li & 7) << 4);
        af[kt] = *reinterpret_cast<const short8v*>(tG + off);
    }

    // ---- gemm1: K=64, C=128; wave owns ct = 2*wave + {0,1} ----
    f32x4 acc1[2];
#pragma unroll
    for (int c = 0; c < 2; ++c) acc1[c] = (f32x4){0.f, 0.f, 0.f, 0.f};
#pragma unroll
    for (int c = 0; c < 2; ++c) {
        const int ct = 2 * wave + c;
#pragma unroll
        for (int kt = 0; kt < 2; ++kt) {
            short8v bfr = *reinterpret_cast<const short8v*>(pw1 + ((size_t)(kt * 8 + ct) * 64 + lane) * 8);
            acc1[c] = __builtin_amdgcn_mfma_f32_16x16x32_bf16(af[kt], bfr, acc1[c], 0, 0, 0);
        }
    }
#pragma unroll
    for (int c = 0; c < 2; ++c) {
        const int ct = 2 * wave + c;
        float bv = bias1[ct * 16 + li];
#pragma unroll
        for (int j = 0; j < 4; ++j) {
            int row = hi * 4 + j;
            unsigned off = (unsigned)(row * 256 + (ct * 16 + li) * 2) ^ ((unsigned)(row & 7) << 4);
            *reinterpret_cast<unsigned short*>(tA + off) = f2bf(fast_tanh(acc1[c][j] + bv));
        }
    }
    __syncthreads();

    // ---- gemm2: K=128, C=128 ----
    short8v af2[4];
#pragma unroll
    for (int kt = 0; kt < 4; ++kt) {
        unsigned off = (unsigned)(li * 256 + (kt * 32 + hi * 8) * 2) ^ ((unsigned)(li & 7) << 4);
        af2[kt] = *reinterpret_cast<const short8v*>(tA + off);
    }
    f32x4 acc2[2];
#pragma unroll
    for (int c = 0; c < 2; ++c) acc2[c] = (f32x4){0.f, 0.f, 0.f, 0.f};
#pragma unroll
    for (int c = 0; c < 2; ++c) {
        const int ct = 2 * wave + c;
#pragma unroll
        for (int kt = 0; kt < 4; ++kt) {
            short8v bfr = *reinterpret_cast<const short8v*>(pw2 + ((size_t)(kt * 8 + ct) * 64 + lane) * 8);
            acc2[c] = __builtin_amdgcn_mfma_f32_16x16x32_bf16(af2[kt], bfr, acc2[c], 0, 0, 0);
        }
    }
#pragma unroll
    for (int c = 0; c < 2; ++c) {
        const int ct = 2 * wave + c;
        float bv = bias2[ct * 16 + li];
#pragma unroll
        for (int j = 0; j < 4; ++j) {
            int row = hi * 4 + j;
            unsigned off = (unsigned)(row * 256 + (ct * 16 + li) * 2) ^ ((unsigned)(row & 7) << 4);
            *reinterpret_cast<unsigned short*>(tB + off) = f2bf(fast_tanh(acc2[c][j] + bv));
        }
    }
    __syncthreads();

    // ---- gemm3: K=128, C=64; wave owns ct = wave ----
    short8v af3[4];
#pragma unroll
    for (int kt = 0; kt < 4; ++kt) {
        unsigned off = (unsigned)(li * 256 + (kt * 32 + hi * 8) * 2) ^ ((unsigned)(li & 7) << 4);
        af3[kt] = *reinterpret_cast<const short8v*>(tB + off);
    }
    f32x4 acc3 = (f32x4){0.f, 0.f, 0.f, 0.f};
#pragma unroll
    for (int kt = 0; kt < 4; ++kt) {
        short8v bfr = *reinterpret_cast<const short8v*>(pw3 + ((size_t)(kt * 4 + wave) * 64 + lane) * 8);
        acc3 = __builtin_amdgcn_mfma_f32_16x16x32_bf16(af3[kt], bfr, acc3, 0, 0, 0);
    }
    {
        float bv = bias3[wave * 16 + li];
#pragma unroll
        for (int j = 0; j < 4; ++j) {
            int row = r0 + hi * 4 + j;
            float v = fast_tanh(fast_tanh(acc3[j] + bv));
            outx[(size_t)row * DIM + wave * 16 + li] = f2bf(v);
        }
    }
}

// ---------------------------------------------------------------------------
// mean pool (node-parallel, bf16 input) + finalize
// ---------------------------------------------------------------------------
__global__ void pool_partial_kernel(const unsigned short* __restrict__ x,
                                    const int* __restrict__ batch,
                                    float* __restrict__ sums) {
    const int tid = threadIdx.x;
    const int d = tid & 63;
    const int rg = tid >> 6;
    int row = blockIdx.x * POOL_ROWS + rg;
    const int rowend = min(N_NODES, (blockIdx.x + 1) * POOL_ROWS);
    float acc = 0.f;
    int cur = -1;
    for (; row < rowend; row += 4) {
        int g = batch[row];
        if (g != cur) {
            if (cur >= 0) atomicAdd(&sums[cur * DIM + d], acc);
            acc = 0.f;
            cur = g;
        }
        acc += bf2f(x[(size_t)row * DIM + d]);
    }
    if (cur >= 0) atomicAdd(&sums[cur * DIM + d], acc);
}

__global__ void pool_final_kernel(const float* __restrict__ sums,
                                  const int* __restrict__ batch,
                                  float* __restrict__ out) {
    const int g = blockIdx.x;
    const int d = threadIdx.x;
    int lo = 0, hi = N_NODES;
    while (lo < hi) { int m = (lo + hi) >> 1; if (batch[m] < g) lo = m + 1; else hi = m; }
    int start = lo;
    hi = N_NODES;
    while (lo < hi) { int m = (lo + hi) >> 1; if (batch[m] < g + 1) lo = m + 1; else hi = m; }
    float cnt = (float)(lo - start);
    out[g * DIM + d] = sums[g * DIM + d] / fmaxf(cnt, 1.f);
}

// ---------------------------------------------------------------------------
extern "C" void kernel_launch(void* const* d_in, const int* in_sizes, int n_in,
                              void* d_out, int out_size, void* d_ws, size_t ws_size,
                              hipStream_t stream) {
    const float* attrs = (const float*)d_in[0];
    const float* W1    = (const float*)d_in[1];
    const float* b1    = (const float*)d_in[2];
    const float* W2    = (const float*)d_in[3];
    const float* b2    = (const float*)d_in[4];
    const float* W3    = (const float*)d_in[5];
    const float* b3    = (const float*)d_in[6];
    const int* edge_index = (const int*)d_in[7];
    const int* batch      = (const int*)d_in[8];
    float* out = (float*)d_out;

    unsigned short* buf0 = (unsigned short*)d_ws;               // N*64 bf16
    unsigned short* buf1 = buf0 + (size_t)N_NODES * DIM;        // N*64 bf16
    unsigned short* pW1  = buf1 + (size_t)N_NODES * DIM;        // 24576
    unsigned short* pW2  = pW1 + 24576;                         // 49152
    unsigned short* pW3  = pW2 + 49152;                         // 24576
    float* psums  = (float*)(pW3 + 24576);                      // G*64 f32
    int* offsets  = (int*)(psums + NGRAPH * DIM);               // N+1
    int* csr_src  = offsets + N_NODES + 1;                      // E
    int* rank     = csr_src + N_EDGES;                          // E
    int* counts   = rank + N_EDGES;                             // N
    int* bsum     = counts + N_NODES;                           // SCAN_NB
    int* bpre     = bsum + SCAN_NB;                             // SCAN_NB

    const int* src = edge_index;
    const int* dst = edge_index + N_EDGES;

    const int edge_blocks = (N_EDGES + 255) / 256;
    const int gnn_blocks  = N_NODES / 16;                       // 3125, exact

    // ---- CSR build (once; edge list is layer-invariant) ----
    hipMemsetAsync(counts, 0, (size_t)N_NODES * sizeof(int), stream);
    count_kernel<<<edge_blocks, 256, 0, stream>>>(dst, counts, rank);
    scan_partial_kernel<<<SCAN_NB, 256, 0, stream>>>(counts, bsum);
    scan_mid_kernel<<<1, 64, 0, stream>>>(bsum, bpre, offsets);
    scan_final_kernel<<<SCAN_NB, 256, 0, stream>>>(counts, bpre, offsets);
    place_kernel<<<edge_blocks, 256, 0, stream>>>(src, dst, rank, offsets, csr_src);

    // ---- weight repack to frag-major bf16 (once) ----
    repack_kernel<DIM, HID><<<(LAYERS * 2 * 8 * 64 + 255) / 256, 256, 0, stream>>>(W1, pW1);
    repack_kernel<HID, HID><<<(LAYERS * 4 * 8 * 64 + 255) / 256, 256, 0, stream>>>(W2, pW2);
    repack_kernel<HID, DIM><<<(LAYERS * 4 * 4 * 64 + 255) / 256, 256, 0, stream>>>(W3, pW3);

    // ---- fused layers, ping-pong: attrs -> buf0 -> buf1 -> buf0 ----
    for (int l = 0; l < LAYERS; ++l) {
        const unsigned short* w1 = pW1 + (size_t)l * 2 * 8 * 64 * 8;
        const unsigned short* w2 = pW2 + (size_t)l * 4 * 8 * 64 * 8;
        const unsigned short* w3 = pW3 + (size_t)l * 4 * 4 * 64 * 8;
        const float* bb1 = b1 + (size_t)l * HID;
        const float* bb2 = b2 + (size_t)l * HID;
        const float* bb3 = b3 + (size_t)l * DIM;
        if (l == 0)
            gnn_layer_kernel<true><<<gnn_blocks, 256, 0, stream>>>(
                attrs, nullptr, offsets, csr_src, w1, bb1, w2, bb2, w3, bb3, buf0);
        else {
            const unsigned short* in = (l == 1) ? buf0 : buf1;
            unsigned short* outb     = (l == 1) ? buf1 : buf0;
            gnn_layer_kernel<false><<<gnn_blocks, 256, 0, stream>>>(
                nullptr, in, offsets, csr_src, w1, bb1, w2, bb2, w3, bb3, outb);
        }
    }

    // ---- mean pool (reads buf0 after layer 2) ----
    hipMemsetAsync(psums, 0, (size_t)NGRAPH * DIM * sizeof(float), stream);
    pool_partial_kernel<<<POOL_NB, 256, 0, stream>>>(buf0, batch, psums);
    pool_final_kernel<<<NGRAPH, DIM, 0, stream>>>(psums, batch, out);
}

// Round 11
// 192.772 us; speedup vs baseline: 1.8369x; 1.1953x over previous
//
#include <hip/hip_runtime.h>
#include <math.h>

#define N_NODES 50000
#define N_EDGES 800000
#define DIM 64
#define HID 128
#define LAYERS 3
#define NGRAPH 128

#define SCAN_TILE 1024
#define SCAN_NB ((N_NODES + SCAN_TILE - 1) / SCAN_TILE)   // 49

#define POOL_ROWS 256
#define POOL_NB ((N_NODES + POOL_ROWS - 1) / POOL_ROWS)   // 196

typedef __attribute__((ext_vector_type(8))) short short8v;   // 8 bf16 (4 VGPR)
typedef __attribute__((ext_vector_type(4))) float f32x4;

__device__ __forceinline__ float bf2f(unsigned short u) {
    return __uint_as_float(((unsigned)u) << 16);
}
__device__ __forceinline__ unsigned short f2bf(float x) {
    unsigned u = __float_as_uint(x);
    unsigned r = (u + 0x7fff + ((u >> 16) & 1)) >> 16;   // RNE
    return (unsigned short)r;
}
// fast tanh: 1 - 2/(1+e^{2x}), clamp |x|<=9; err ~1e-6 << bf16 rounding
__device__ __forceinline__ float fast_tanh(float x) {
    float xc = fminf(fmaxf(x, -9.0f), 9.0f);
    float y = __expf(2.0f * xc);
    return 1.0f - 2.0f * __builtin_amdgcn_rcpf(y + 1.0f);
}

// ---------------------------------------------------------------------------
// CSR build. count records each edge's rank (atomicAdd return) so place
// needs no atomic. csr entries are uint16 (src < 65536): 1.6 MB buffer
// fits per-XCD L2 -> write amplification drops (round-10: 52 MB HBM writes
// for a 3.2 MB int buffer).
// ---------------------------------------------------------------------------
__global__ void count_kernel(const int* __restrict__ dst,
                             int* __restrict__ counts,
                             int* __restrict__ rank) {
    int e = blockIdx.x * blockDim.x + threadIdx.x;
    if (e >= N_EDGES) return;
    rank[e] = atomicAdd(&counts[dst[e]], 1);
}

__global__ void scan_partial_kernel(const int* __restrict__ counts,
                                    int* __restrict__ bsum) {
    __shared__ int red[256];
    const int b = blockIdx.x, tid = threadIdx.x;
    const int base = b * SCAN_TILE + tid * 4;
    int s = 0;
    if (base + 3 < N_NODES) {
        int4 v = *reinterpret_cast<const int4*>(counts + base);
        s = v.x + v.y + v.z + v.w;
    } else {
        for (int i = 0; i < 4; ++i)
            if (base + i < N_NODES) s += counts[base + i];
    }
    red[tid] = s;
    __syncthreads();
    for (int off = 128; off > 0; off >>= 1) {
        if (tid < off) red[tid] += red[tid + off];
        __syncthreads();
    }
    if (tid == 0) bsum[b] = red[0];
}

__global__ void scan_mid_kernel(const int* __restrict__ bsum,
                                int* __restrict__ bpre,
                                int* __restrict__ offsets) {
    int tid = threadIdx.x;   // 64 threads, one wave
    int orig = (tid < SCAN_NB) ? bsum[tid] : 0;
    int v = orig;
    for (int off = 1; off < 64; off <<= 1) {
        int u = __shfl_up(v, off);
        if (tid >= off) v += u;
    }
    if (tid < SCAN_NB) bpre[tid] = v - orig;
    if (tid == 0) offsets[N_NODES] = N_EDGES;
}

__global__ void scan_final_kernel(const int* __restrict__ counts,
                                  const int* __restrict__ bpre,
                                  int* __restrict__ offsets) {
    __shared__ int pre[256];
    const int b = blockIdx.x, tid = threadIdx.x;
    const int base = b * SCAN_TILE + tid * 4;
    int c[4];
    int s = 0;
#pragma unroll
    for (int i = 0; i < 4; ++i) {
        c[i] = (base + i < N_NODES) ? counts[base + i] : 0;
        s += c[i];
    }
    pre[tid] = s;
    __syncthreads();
    for (int off = 1; off < 256; off <<= 1) {
        int v = (tid >= off) ? pre[tid - off] : 0;
        __syncthreads();
        pre[tid] += v;
        __syncthreads();
    }
    int run = bpre[b] + pre[tid] - s;
#pragma unroll
    for (int i = 0; i < 4; ++i) {
        if (base + i < N_NODES) {
            offsets[base + i] = run;
            run += c[i];
        }
    }
}

__global__ void place_kernel(const int* __restrict__ src,
                             const int* __restrict__ dst,
                             const int* __restrict__ rank,
                             const int* __restrict__ offsets,
                             unsigned short* __restrict__ csr_src) {
    int e = blockIdx.x * blockDim.x + threadIdx.x;
    if (e >= N_EDGES) return;
    csr_src[offsets[dst[e]] + rank[e]] = (unsigned short)src[e];
}

// ---------------------------------------------------------------------------
// weight repack: W[L][K][C] f32 -> frag-major bf16 P[L][KT][CT][64 lanes][8]
// lane l (li=l&15, hi=l>>4) gets W[kt*32 + hi*8 + j][ct*16 + li], j=0..7
// ---------------------------------------------------------------------------
template<int K, int C>
__global__ void repack_kernel(const float* __restrict__ W, unsigned short* __restrict__ P) {
    constexpr int KT = K / 32, CT = C / 16;
    int t = blockIdx.x * 256 + threadIdx.x;
    if (t >= LAYERS * KT * CT * 64) return;
    int lane = t & 63; int rest = t >> 6;
    int ct = rest % CT; rest /= CT;
    int kt = rest % KT; int l = rest / KT;
    int li = lane & 15, hi = lane >> 4;
    const float* Wl = W + (size_t)l * K * C;
    short8v o;
#pragma unroll
    for (int j = 0; j < 8; ++j)
        o[j] = (short)f2bf(Wl[(size_t)(kt * 32 + hi * 8 + j) * C + ct * 16 + li]);
    *reinterpret_cast<short8v*>(P + ((size_t)l * KT * CT * 64 + (size_t)(kt * CT + ct) * 64 + lane) * 8) = o;
}

// ---------------------------------------------------------------------------
// fused GIN layer: edge-walk gather (16 thr/node, unroll-4 pipelined, f32
// acc) -> agg LDS tile -> MFMA W1 -> tanh -> LDS xpose -> MFMA W2 -> tanh
// -> xpose -> MFMA W3 -> tanh(tanh) -> out. block = 16 rows, 4 waves C-split.
// IN and OUT are DISTINCT buffers (ping-pong) — in-place races (round-6 bug).
// Edge loop is unrolled x4 so each 16-lane group keeps 4 independent row
// loads in flight (round-10: 1 in flight -> latency-bound at 54% occupancy).
// Frag convention (matches repack): k = kt*32 + hi*8 + j, row/col = li.
// D convention (m89): col = li, row = hi*4 + j.
// LDS tiles swizzled byte ^= (row&7)<<4 (G4/T2).
// ---------------------------------------------------------------------------
template<bool F32IN>
__global__ __launch_bounds__(256) void gnn_layer_kernel(
        const float* __restrict__ xf, const unsigned short* __restrict__ xb,
        const int* __restrict__ offsets, const unsigned short* __restrict__ csr_src,
        const unsigned short* __restrict__ pw1, const float* __restrict__ bias1,
        const unsigned short* __restrict__ pw2, const float* __restrict__ bias2,
        const unsigned short* __restrict__ pw3, const float* __restrict__ bias3,
        unsigned short* __restrict__ outx) {
    __shared__ unsigned short agg[16 * 64];      // 2 KB
    __shared__ unsigned short tileA[16 * 128];   // 4 KB
    __shared__ unsigned short tileB[16 * 128];   // 4 KB
    const int tid = threadIdx.x;
    const int wave = tid >> 6, lane = tid & 63;
    const int li = lane & 15, hi = lane >> 4;
    const int r0 = blockIdx.x * 16;              // 3125*16 == N exactly
    char* tG = reinterpret_cast<char*>(agg);
    char* tA = reinterpret_cast<char*>(tileA);
    char* tB = reinterpret_cast<char*>(tileB);

    // ---- phase 1: gather. 16 threads per node, 4 channels each ----
    {
        const int nr = tid >> 4;                 // node row 0..15
        const int q  = tid & 15;                 // channel group (4 ch)
        const int n  = r0 + nr;
        float a0, a1, a2, a3;
        if (F32IN) {
            float4 v = *reinterpret_cast<const float4*>(xf + (size_t)n * DIM + q * 4);
            a0 = v.x; a1 = v.y; a2 = v.z; a3 = v.w;
        } else {
            ushort4 v = *reinterpret_cast<const ushort4*>(xb + (size_t)n * DIM + q * 4);
            a0 = bf2f(v.x); a1 = bf2f(v.y); a2 = bf2f(v.z); a3 = bf2f(v.w);
        }
        int p = offsets[n];
        const int pe = offsets[n + 1];
        // unroll-4 pipeline: 4 independent row loads in flight per group
        for (; p + 4 <= pe; p += 4) {
            int s0 = csr_src[p + 0];
            int s1 = csr_src[p + 1];
            int s2 = csr_src[p + 2];
            int s3 = csr_src[p + 3];
            if (F32IN) {
                float4 v0 = *reinterpret_cast<const float4*>(xf + (size_t)s0 * DIM + q * 4);
                float4 v1 = *reinterpret_cast<const float4*>(xf + (size_t)s1 * DIM + q * 4);
                float4 v2 = *reinterpret_cast<const float4*>(xf + (size_t)s2 * DIM + q * 4);
                float4 v3 = *reinterpret_cast<const float4*>(xf + (size_t)s3 * DIM + q * 4);
                a0 += v0.x + v1.x + v2.x + v3.x;
                a1 += v0.y + v1.y + v2.y + v3.y;
                a2 += v0.z + v1.z + v2.z + v3.z;
                a3 += v0.w + v1.w + v2.w + v3.w;
            } else {
                ushort4 v0 = *reinterpret_cast<const ushort4*>(xb + (size_t)s0 * DIM + q * 4);
                ushort4 v1 = *reinterpret_cast<const ushort4*>(xb + (size_t)s1 * DIM + q * 4);
                ushort4 v2 = *reinterpret_cast<const ushort4*>(xb + (size_t)s2 * DIM + q * 4);
                ushort4 v3 = *reinterpret_cast<const ushort4*>(xb + (size_t)s3 * DIM + q * 4);
                a0 += bf2f(v0.x) + bf2f(v1.x) + bf2f(v2.x) + bf2f(v3.x);
                a1 += bf2f(v0.y) + bf2f(v1.y) + bf2f(v2.y) + bf2f(v3.y);
                a2 += bf2f(v0.z) + bf2f(v1.z) + bf2f(v2.z) + bf2f(v3.z);
                a3 += bf2f(v0.w) + bf2f(v1.w) + bf2f(v2.w) + bf2f(v3.w);
            }
        }
        for (; p < pe; ++p) {
            int s = csr_src[p];
            if (F32IN) {
                float4 v = *reinterpret_cast<const float4*>(xf + (size_t)s * DIM + q * 4);
                a0 += v.x; a1 += v.y; a2 += v.z; a3 += v.w;
            } else {
                ushort4 v = *reinterpret_cast<const ushort4*>(xb + (size_t)s * DIM + q * 4);
                a0 += bf2f(v.x); a1 += bf2f(v.y); a2 += bf2f(v.z); a3 += bf2f(v.w);
            }
        }
        ushort4 o;
        o.x = f2bf(a0); o.y = f2bf(a1); o.z = f2bf(a2); o.w = f2bf(a3);
        unsigned off = (unsigned)(nr * 128 + q * 8) ^ ((unsigned)(nr & 7) << 4);
        *reinterpret_cast<ushort4*>(tG + off) = o;
    }
    __syncthreads();

    // ---- A-frags from agg tile (row = li, k = kt*32 + hi*8 + j) ----
    short8v af[2];
#pragma unroll
    for (int kt = 0; kt < 2; ++kt) {
        unsigned off = (unsigned)(li * 128 + (kt * 32 + hi * 8) * 2) ^ ((unsigned)(li & 7) << 4);
        af[kt] = *reinterpret_cast<const short8v*>(tG + off);
    }

    // ---- gemm1: K=64, C=128; wave owns ct = 2*wave + {0,1} ----
    f32x4 acc1[2];
#pragma unroll
    for (int c = 0; c < 2; ++c) acc1[c] = (f32x4){0.f, 0.f, 0.f, 0.f};
#pragma unroll
    for (int c = 0; c < 2; ++c) {
        const int ct = 2 * wave + c;
#pragma unroll
        for (int kt = 0; kt < 2; ++kt) {
            short8v bfr = *reinterpret_cast<const short8v*>(pw1 + ((size_t)(kt * 8 + ct) * 64 + lane) * 8);
            acc1[c] = __builtin_amdgcn_mfma_f32_16x16x32_bf16(af[kt], bfr, acc1[c], 0, 0, 0);
        }
    }
#pragma unroll
    for (int c = 0; c < 2; ++c) {
        const int ct = 2 * wave + c;
        float bv = bias1[ct * 16 + li];
#pragma unroll
        for (int j = 0; j < 4; ++j) {
            int row = hi * 4 + j;
            unsigned off = (unsigned)(row * 256 + (ct * 16 + li) * 2) ^ ((unsigned)(row & 7) << 4);
            *reinterpret_cast<unsigned short*>(tA + off) = f2bf(fast_tanh(acc1[c][j] + bv));
        }
    }
    __syncthreads();

    // ---- gemm2: K=128, C=128 ----
    short8v af2[4];
#pragma unroll
    for (int kt = 0; kt < 4; ++kt) {
        unsigned off = (unsigned)(li * 256 + (kt * 32 + hi * 8) * 2) ^ ((unsigned)(li & 7) << 4);
        af2[kt] = *reinterpret_cast<const short8v*>(tA + off);
    }
    f32x4 acc2[2];
#pragma unroll
    for (int c = 0; c < 2; ++c) acc2[c] = (f32x4){0.f, 0.f, 0.f, 0.f};
#pragma unroll
    for (int c = 0; c < 2; ++c) {
        const int ct = 2 * wave + c;
#pragma unroll
        for (int kt = 0; kt < 4; ++kt) {
            short8v bfr = *reinterpret_cast<const short8v*>(pw2 + ((size_t)(kt * 8 + ct) * 64 + lane) * 8);
            acc2[c] = __builtin_amdgcn_mfma_f32_16x16x32_bf16(af2[kt], bfr, acc2[c], 0, 0, 0);
        }
    }
#pragma unroll
    for (int c = 0; c < 2; ++c) {
        const int ct = 2 * wave + c;
        float bv = bias2[ct * 16 + li];
#pragma unroll
        for (int j = 0; j < 4; ++j) {
            int row = hi * 4 + j;
            unsigned off = (unsigned)(row * 256 + (ct * 16 + li) * 2) ^ ((unsigned)(row & 7) << 4);
            *reinterpret_cast<unsigned short*>(tB + off) = f2bf(fast_tanh(acc2[c][j] + bv));
        }
    }
    __syncthreads();

    // ---- gemm3: K=128, C=64; wave owns ct = wave ----
    short8v af3[4];
#pragma unroll
    for (int kt = 0; kt < 4; ++kt) {
        unsigned off = (unsigned)(li * 256 + (kt * 32 + hi * 8) * 2) ^ ((unsigned)(li & 7) << 4);
        af3[kt] = *reinterpret_cast<const short8v*>(tB + off);
    }
    f32x4 acc3 = (f32x4){0.f, 0.f, 0.f, 0.f};
#pragma unroll
    for (int kt = 0; kt < 4; ++kt) {
        short8v bfr = *reinterpret_cast<const short8v*>(pw3 + ((size_t)(kt * 4 + wave) * 64 + lane) * 8);
        acc3 = __builtin_amdgcn_mfma_f32_16x16x32_bf16(af3[kt], bfr, acc3, 0, 0, 0);
    }
    {
        float bv = bias3[wave * 16 + li];
#pragma unroll
        for (int j = 0; j < 4; ++j) {
            int row = r0 + hi * 4 + j;
            float v = fast_tanh(fast_tanh(acc3[j] + bv));
            outx[(size_t)row * DIM + wave * 16 + li] = f2bf(v);
        }
    }
}

// ---------------------------------------------------------------------------
// mean pool (node-parallel, bf16 input) + finalize
// ---------------------------------------------------------------------------
__global__ void pool_partial_kernel(const unsigned short* __restrict__ x,
                                    const int* __restrict__ batch,
                                    float* __restrict__ sums) {
    const int tid = threadIdx.x;
    const int d = tid & 63;
    const int rg = tid >> 6;
    int row = blockIdx.x * POOL_ROWS + rg;
    const int rowend = min(N_NODES, (blockIdx.x + 1) * POOL_ROWS);
    float acc = 0.f;
    int cur = -1;
    for (; row < rowend; row += 4) {
        int g = batch[row];
        if (g != cur) {
            if (cur >= 0) atomicAdd(&sums[cur * DIM + d], acc);
            acc = 0.f;
            cur = g;
        }
        acc += bf2f(x[(size_t)row * DIM + d]);
    }
    if (cur >= 0) atomicAdd(&sums[cur * DIM + d], acc);
}

__global__ void pool_final_kernel(const float* __restrict__ sums,
                                  const int* __restrict__ batch,
                                  float* __restrict__ out) {
    const int g = blockIdx.x;
    const int d = threadIdx.x;
    int lo = 0, hi = N_NODES;
    while (lo < hi) { int m = (lo + hi) >> 1; if (batch[m] < g) lo = m + 1; else hi = m; }
    int start = lo;
    hi = N_NODES;
    while (lo < hi) { int m = (lo + hi) >> 1; if (batch[m] < g + 1) lo = m + 1; else hi = m; }
    float cnt = (float)(lo - start);
    out[g * DIM + d] = sums[g * DIM + d] / fmaxf(cnt, 1.f);
}

// ---------------------------------------------------------------------------
extern "C" void kernel_launch(void* const* d_in, const int* in_sizes, int n_in,
                              void* d_out, int out_size, void* d_ws, size_t ws_size,
                              hipStream_t stream) {
    const float* attrs = (const float*)d_in[0];
    const float* W1    = (const float*)d_in[1];
    const float* b1    = (const float*)d_in[2];
    const float* W2    = (const float*)d_in[3];
    const float* b2    = (const float*)d_in[4];
    const float* W3    = (const float*)d_in[5];
    const float* b3    = (const float*)d_in[6];
    const int* edge_index = (const int*)d_in[7];
    const int* batch      = (const int*)d_in[8];
    float* out = (float*)d_out;

    unsigned short* buf0 = (unsigned short*)d_ws;               // N*64 bf16
    unsigned short* buf1 = buf0 + (size_t)N_NODES * DIM;        // N*64 bf16
    unsigned short* pW1  = buf1 + (size_t)N_NODES * DIM;        // 24576
    unsigned short* pW2  = pW1 + 24576;                         // 49152
    unsigned short* pW3  = pW2 + 49152;                         // 24576
    float* psums  = (float*)(pW3 + 24576);                      // G*64 f32
    int* offsets  = (int*)(psums + NGRAPH * DIM);               // N+1
    unsigned short* csr16 = (unsigned short*)(offsets + N_NODES + 1);  // E u16
    int* rank     = (int*)(csr16 + N_EDGES);                    // E (2B*E even -> 4B aligned)
    int* counts   = rank + N_EDGES;                             // N
    int* bsum     = counts + N_NODES;                           // SCAN_NB
    int* bpre     = bsum + SCAN_NB;                             // SCAN_NB

    const int* src = edge_index;
    const int* dst = edge_index + N_EDGES;

    const int edge_blocks = (N_EDGES + 255) / 256;
    const int gnn_blocks  = N_NODES / 16;                       // 3125, exact

    // ---- CSR build (once; edge list is layer-invariant) ----
    hipMemsetAsync(counts, 0, (size_t)N_NODES * sizeof(int), stream);
    count_kernel<<<edge_blocks, 256, 0, stream>>>(dst, counts, rank);
    scan_partial_kernel<<<SCAN_NB, 256, 0, stream>>>(counts, bsum);
    scan_mid_kernel<<<1, 64, 0, stream>>>(bsum, bpre, offsets);
    scan_final_kernel<<<SCAN_NB, 256, 0, stream>>>(counts, bpre, offsets);
    place_kernel<<<edge_blocks, 256, 0, stream>>>(src, dst, rank, offsets, csr16);

    // ---- weight repack to frag-major bf16 (once) ----
    repack_kernel<DIM, HID><<<(LAYERS * 2 * 8 * 64 + 255) / 256, 256, 0, stream>>>(W1, pW1);
    repack_kernel<HID, HID><<<(LAYERS * 4 * 8 * 64 + 255) / 256, 256, 0, stream>>>(W2, pW2);
    repack_kernel<HID, DIM><<<(LAYERS * 4 * 4 * 64 + 255) / 256, 256, 0, stream>>>(W3, pW3);

    // ---- fused layers, ping-pong: attrs -> buf0 -> buf1 -> buf0 ----
    for (int l = 0; l < LAYERS; ++l) {
        const unsigned short* w1 = pW1 + (size_t)l * 2 * 8 * 64 * 8;
        const unsigned short* w2 = pW2 + (size_t)l * 4 * 8 * 64 * 8;
        const unsigned short* w3 = pW3 + (size_t)l * 4 * 4 * 64 * 8;
        const float* bb1 = b1 + (size_t)l * HID;
        const float* bb2 = b2 + (size_t)l * HID;
        const float* bb3 = b3 + (size_t)l * DIM;
        if (l == 0)
            gnn_layer_kernel<true><<<gnn_blocks, 256, 0, stream>>>(
                attrs, nullptr, offsets, csr16, w1, bb1, w2, bb2, w3, bb3, buf0);
        else {
            const unsigned short* in = (l == 1) ? buf0 : buf1;
            unsigned short* outb     = (l == 1) ? buf1 : buf0;
            gnn_layer_kernel<false><<<gnn_blocks, 256, 0, stream>>>(
                nullptr, in, offsets, csr16, w1, bb1, w2, bb2, w3, bb3, outb);
        }
    }

    // ---- mean pool (reads buf0 after layer 2) ----
    hipMemsetAsync(psums, 0, (size_t)NGRAPH * DIM * sizeof(float), stream);
    pool_partial_kernel<<<POOL_NB, 256, 0, stream>>>(buf0, batch, psums);
    pool_final_kernel<<<NGRAPH, DIM, 0, stream>>>(psums, batch, out);
}